// Round 1
// baseline (2182.823 us; speedup 1.0000x reference)
//
#include <hip/hip_runtime.h>
#include <math.h>

#define SQ2PI_F 0.79788456f

// ------------------------------------------------------------------
// small kernels
// ------------------------------------------------------------------

__global__ void k_tanh_half(const float* __restrict__ w, float* __restrict__ m, int n) {
  int i = blockIdx.x * 256 + threadIdx.x;
  if (i < n) m[i] = tanhf(0.5f * w[i]);
}

// s[j] = sum_i (1 - m[i][j]^2), m is rows x 256, launched <<<1,256>>>
__global__ void k_colsum(const float* __restrict__ m, float* __restrict__ s, int rows) {
  int j = threadIdx.x;
  float acc = 0.f;
  for (int i = 0; i < rows; ++i) {
    float v = m[i * 256 + j];
    acc = fmaf(-v, v, acc + 1.0f);
  }
  s[j] = acc;
}

// layer-2 small pass: diagsig2 = d1 @ (m1*m1) + s1 ; h2 = x1bar @ m1 + th1
// -> x2bar, c2, d2p.  grid 256 (rows), block 256 (cols)
__global__ void k_layer2_small(const float* __restrict__ d1, const float* __restrict__ x1bar,
                               const float* __restrict__ m1, const float* __restrict__ s1,
                               const float* __restrict__ th1,
                               float* __restrict__ x2bar, float* __restrict__ c2,
                               float* __restrict__ d2p) {
  int r = blockIdx.x, i = threadIdx.x;
  float accd = 0.f, acch = 0.f;
  for (int j = 0; j < 256; ++j) {
    float mm = m1[j * 256 + i];
    accd = fmaf(d1[r * 256 + j] * mm, mm, accd);
    acch = fmaf(x1bar[r * 256 + j], mm, acch);
  }
  float rs = rsqrtf(accd + s1[i]);
  float xb = tanhf(SQ2PI_F * (acch + th1[i]) * rs);
  x2bar[r * 256 + i] = xb;
  float d = 1.f - xb * xb;
  c2[r * 256 + i] = d * rs;
  d2p[r * 256 + i] = d;
}

// layer-3 small pass: diagsig3[r,i] = sum_j m2[j,i]*t3[r,j,i] + s2[i];
//                     h3 = x2bar @ m2 + th2 -> x3bar, c3, d3p
__global__ void k_layer3_small(const float* __restrict__ t3, const float* __restrict__ m2,
                               const float* __restrict__ x2bar, const float* __restrict__ s2,
                               const float* __restrict__ th2,
                               float* __restrict__ x3bar, float* __restrict__ c3,
                               float* __restrict__ d3p) {
  int r = blockIdx.x, i = threadIdx.x;
  const float* t3b = t3 + (size_t)r * 65536;
  float accd = 0.f, acch = 0.f;
  for (int j = 0; j < 256; ++j) {
    float mm = m2[j * 256 + i];
    accd = fmaf(mm, t3b[j * 256 + i], accd);
    acch = fmaf(x2bar[r * 256 + j], mm, acch);
  }
  float rs = rsqrtf(accd + s2[i]);
  float xb = tanhf(SQ2PI_F * (acch + th2[i]) * rs);
  x3bar[r * 256 + i] = xb;
  float d = 1.f - xb * xb;
  c3[r * 256 + i] = d * rs;
  d3p[r * 256 + i] = d;
}

// final layer + log_softmax + loss + frac_correct. <<<1,256>>>, thread = row
__global__ void k_final(const float* __restrict__ x3bar, const float* __restrict__ mlast,
                        const float* __restrict__ thlast, const int* __restrict__ target,
                        float* __restrict__ hlast_out, float* __restrict__ logp_out,
                        float* __restrict__ loss_out, float* __restrict__ frac_out) {
  __shared__ float Wl[2560];
  __shared__ float red[256];
  int t = threadIdx.x;
  for (int p = t; p < 2560; p += 256) Wl[p] = mlast[p];
  __syncthreads();
  int r = t;
  float acc[10];
#pragma unroll
  for (int c = 0; c < 10; ++c) acc[c] = thlast[c];
  for (int j = 0; j < 256; ++j) {
    float xv = x3bar[r * 256 + j];
#pragma unroll
    for (int c = 0; c < 10; ++c) acc[c] = fmaf(xv, Wl[j * 10 + c], acc[c]);
  }
#pragma unroll
  for (int c = 0; c < 10; ++c) hlast_out[r * 10 + c] = acc[c];
  float mx = acc[0];
  int am = 0;
#pragma unroll
  for (int c = 1; c < 10; ++c)
    if (acc[c] > mx) { mx = acc[c]; am = c; }
  float se = 0.f;
#pragma unroll
  for (int c = 0; c < 10; ++c) se += expf(acc[c] - mx);
  float lse = logf(se);
#pragma unroll
  for (int c = 0; c < 10; ++c) logp_out[r * 10 + c] = acc[c] - mx - lse;
  int tg = target[r];
  float lossc = -(acc[tg] - mx - lse);
  float corr = (am == tg) ? 1.f : 0.f;
  red[t] = lossc;
  __syncthreads();
  for (int s = 128; s > 0; s >>= 1) {
    if (t < s) red[t] += red[t + s];
    __syncthreads();
  }
  if (t == 0) loss_out[0] = red[0] * (1.f / 256.f);
  __syncthreads();
  red[t] = corr;
  __syncthreads();
  for (int s = 128; s > 0; s >>= 1) {
    if (t < s) red[t] += red[t + s];
    __syncthreads();
  }
  if (t == 0) frac_out[0] = red[0] * (1.f / 256.f);
}

// ------------------------------------------------------------------
// tiled fp32 GEMM, 128x128 block tile, 8x8 per thread, 256 threads.
// MODE 0: layer1. A = x (M x K row-major, transpose-stage), B = m0.
//         epilogue: x1bar = tanh(SQ2PI*(acc+th0[c])*rsqrt(diagsig1[c])); d1 = 1-x1bar^2
// MODE 5: gram.    A = m1 (K x M, direct), B = m1 row-weighted by d1[b,k].
//         epilogue: xcov2 = SQ2PI*c2_i*c2_l*(acc + (i==l)*s1) + (i==l)*d2p
// MODE 6: t3.      A = xcov2[b] (M x K, transpose-stage), B = m2. plain store.
// MODE 8: sigma3.  A = m2 (K x M, direct), B = t3[b].
//         epilogue: xcov3 = SQ2PI*c3_i*c3_l*(acc + (i==l)*s2) + (i==l)*d3p
// ------------------------------------------------------------------
template <int MODE>
__global__ __launch_bounds__(256, 4) void gemm_tile(
    const float* __restrict__ A, const float* __restrict__ B,
    const float* __restrict__ w, const float* __restrict__ v0,
    const float* __restrict__ v1, const float* __restrict__ v2,
    float* __restrict__ out0, float* __restrict__ out1, int K, int lda) {
  constexpr int BK = 16;
  __shared__ float As[BK][128];
  __shared__ float Bs[BK][128];

  const int tid = threadIdx.x;
  const int tx = tid & 15;
  const int ty = tid >> 4;
  const int b = blockIdx.z;
  const int r0 = blockIdx.y * 128;
  const int c0 = blockIdx.x * 128;

  const float* Ab = A;
  const float* Bb = B;
  if (MODE == 6) Ab = A + (size_t)b * 65536;
  if (MODE == 8) Bb = B + (size_t)b * 65536;

  const int kA = tid >> 4;          // direct staging row (0..15)
  const int mA = (tid & 15) * 8;    // direct staging col base
  const int jr = tid & 127;         // transpose staging row
  const int kq = (tid >> 7) * 8;    // transpose staging col base (0|8)

  float pa[8], pb[8], wv = 1.f;

  auto load_tile = [&](int kt) {
    if (MODE == 0 || MODE == 6) {
      const float* p = Ab + (size_t)(r0 + jr) * lda + kt + kq;
      *(float4*)&pa[0] = *(const float4*)p;
      *(float4*)&pa[4] = *(const float4*)(p + 4);
    } else {
      const float* p = Ab + (size_t)(kt + kA) * lda + r0 + mA;
      *(float4*)&pa[0] = *(const float4*)p;
      *(float4*)&pa[4] = *(const float4*)(p + 4);
    }
    const float* q = Bb + (size_t)(kt + kA) * 256 + c0 + mA;
    *(float4*)&pb[0] = *(const float4*)q;
    *(float4*)&pb[4] = *(const float4*)(q + 4);
    if (MODE == 5) wv = w[b * 256 + kt + kA];
  };

  float acc[8][8];
#pragma unroll
  for (int i = 0; i < 8; ++i)
#pragma unroll
    for (int j = 0; j < 8; ++j) acc[i][j] = 0.f;

  load_tile(0);
  const int ntk = K / BK;
  for (int t = 0; t < ntk; ++t) {
    __syncthreads();
    if (MODE == 0 || MODE == 6) {
#pragma unroll
      for (int e = 0; e < 8; ++e) As[kq + e][jr] = pa[e];
    } else {
      *(float4*)&As[kA][mA] = *(float4*)&pa[0];
      *(float4*)&As[kA][mA + 4] = *(float4*)&pa[4];
    }
    if (MODE == 5) {
#pragma unroll
      for (int e = 0; e < 8; ++e) pb[e] *= wv;
    }
    *(float4*)&Bs[kA][mA] = *(float4*)&pb[0];
    *(float4*)&Bs[kA][mA + 4] = *(float4*)&pb[4];
    __syncthreads();
    if (t + 1 < ntk) load_tile((t + 1) * BK);
#pragma unroll
    for (int kk = 0; kk < BK; ++kk) {
      float af[8], bf[8];
      *(float4*)&af[0] = *(const float4*)&As[kk][ty * 8];
      *(float4*)&af[4] = *(const float4*)&As[kk][ty * 8 + 4];
      *(float4*)&bf[0] = *(const float4*)&Bs[kk][tx * 8];
      *(float4*)&bf[4] = *(const float4*)&Bs[kk][tx * 8 + 4];
#pragma unroll
      for (int i = 0; i < 8; ++i)
#pragma unroll
        for (int j = 0; j < 8; ++j) acc[i][j] = fmaf(af[i], bf[j], acc[i][j]);
    }
  }

#pragma unroll
  for (int i = 0; i < 8; ++i) {
    const int r = r0 + ty * 8 + i;
    float row[8], row2[8];
#pragma unroll
    for (int j = 0; j < 8; ++j) {
      const int c = c0 + tx * 8 + j;
      float g = acc[i][j];
      if (MODE == 0) {
        float rs = rsqrtf(v0[c]);
        float xb = tanhf(SQ2PI_F * (g + v1[c]) * rs);
        row[j] = xb;
        row2[j] = 1.f - xb * xb;
      } else if (MODE == 6) {
        row[j] = g;
      } else {  // 5, 8
        float ci = v0[b * 256 + r];
        float cl = v0[b * 256 + c];
        if (r == c) g += v1[r];
        row[j] = SQ2PI_F * ci * cl * g + ((r == c) ? v2[b * 256 + c] : 0.f);
      }
    }
    size_t o = (MODE == 0) ? ((size_t)r * 256 + c0 + tx * 8)
                           : ((size_t)b * 65536 + (size_t)r * 256 + c0 + tx * 8);
    *(float4*)&out0[o] = *(float4*)&row[0];
    *(float4*)&out0[o + 4] = *(float4*)&row[4];
    if (MODE == 0) {
      *(float4*)&out1[o] = *(float4*)&row2[0];
      *(float4*)&out1[o + 4] = *(float4*)&row2[4];
    }
  }
}

// ------------------------------------------------------------------

extern "C" void kernel_launch(void* const* d_in, const int* in_sizes, int n_in,
                              void* d_out, int out_size, void* d_ws, size_t ws_size,
                              hipStream_t stream) {
  const float* x = (const float*)d_in[0];
  const int* target = (const int*)d_in[1];
  const float* w0 = (const float*)d_in[2];
  const float* w1 = (const float*)d_in[3];
  const float* w2 = (const float*)d_in[4];
  const float* wlast = (const float*)d_in[5];
  const float* th0 = (const float*)d_in[6];
  const float* th1 = (const float*)d_in[7];
  const float* th2 = (const float*)d_in[8];
  const float* thlast = (const float*)d_in[9];

  float* W = (float*)d_ws;
  size_t o = 0;
  auto alloc = [&](size_t n) { float* p = W + o; o += n; return p; };
  float* m0 = alloc(200704);
  float* m1 = alloc(65536);
  float* m2 = alloc(65536);
  float* mlast = alloc(2560);
  float* diagsig1 = alloc(256);
  float* s1 = alloc(256);
  float* s2 = alloc(256);
  float* x1bar = alloc(65536);
  float* d1 = alloc(65536);
  float* x2bar = alloc(65536);
  float* c2 = alloc(65536);
  float* d2p = alloc(65536);
  float* x3bar = alloc(65536);
  float* c3 = alloc(65536);
  float* d3p = alloc(65536);
  o = (o + 63) & ~(size_t)63;
  float* bufA = alloc(16777216);  // xcov2 (and xcov3 in small-ws path)
  bool big_ws = (ws_size >= (o + 16777216 + 64) * sizeof(float));
  float* bufB = big_ws ? alloc(16777216) : nullptr;

  float* hlast = (float*)d_out;
  float* logp = hlast + 2560;
  float* xcov3_out = logp + 2560;
  float* loss = xcov3_out + 16777216;
  float* frac = loss + 1;

  float* t3 = big_ws ? bufB : xcov3_out;        // t3 scratch
  float* xcov3_dst = big_ws ? xcov3_out : bufA; // where mode-8 writes

  // 1) m = tanh(w/2)
  k_tanh_half<<<784, 256, 0, stream>>>(w0, m0, 200704);
  k_tanh_half<<<256, 256, 0, stream>>>(w1, m1, 65536);
  k_tanh_half<<<256, 256, 0, stream>>>(w2, m2, 65536);
  k_tanh_half<<<10, 256, 0, stream>>>(wlast, mlast, 2560);

  // 2) column sums
  k_colsum<<<1, 256, 0, stream>>>(m0, diagsig1, 784);
  k_colsum<<<1, 256, 0, stream>>>(m1, s1, 256);
  k_colsum<<<1, 256, 0, stream>>>(m2, s2, 256);

  // 3) layer 1: x1bar, d1
  gemm_tile<0><<<dim3(2, 2, 1), 256, 0, stream>>>(x, m0, nullptr, diagsig1, th0,
                                                  nullptr, x1bar, d1, 784, 784);

  // 4) layer 2 small: x2bar, c2, d2p
  k_layer2_small<<<256, 256, 0, stream>>>(d1, x1bar, m1, s1, th1, x2bar, c2, d2p);

  // 5) xcov2 (fused gram + epilogue)
  gemm_tile<5><<<dim3(2, 2, 256), 256, 0, stream>>>(m1, m1, d1, c2, s1, d2p,
                                                    bufA, nullptr, 256, 256);

  // 6) t3 = xcov2 @ m2
  gemm_tile<6><<<dim3(2, 2, 256), 256, 0, stream>>>(bufA, m2, nullptr, nullptr,
                                                    nullptr, nullptr, t3, nullptr,
                                                    256, 256);

  // 7) layer 3 small: x3bar, c3, d3p
  k_layer3_small<<<256, 256, 0, stream>>>(t3, m2, x2bar, s2, th2, x3bar, c3, d3p);

  // 8) xcov3 (fused sigma3 + epilogue)
  gemm_tile<8><<<dim3(2, 2, 256), 256, 0, stream>>>(m2, t3, nullptr, c3, s2, d3p,
                                                    xcov3_dst, nullptr, 256, 256);
  if (!big_ws) {
    hipMemcpyAsync(xcov3_out, bufA, (size_t)16777216 * sizeof(float),
                   hipMemcpyDeviceToDevice, stream);
  }

  // 9) final layer + softmax + loss + acc
  k_final<<<1, 256, 0, stream>>>(x3bar, mlast, thlast, target, hlast, logp, loss, frac);
}

// Round 2
// 511.331 us; speedup vs baseline: 4.2689x; 4.2689x over previous
//
#include <hip/hip_runtime.h>
#include <math.h>

#define SQ2PI_F 0.79788456f

// ------------------------------------------------------------------
// small kernels
// ------------------------------------------------------------------

__global__ void k_zero(float* __restrict__ p, int n) {
  int i = blockIdx.x * 256 + threadIdx.x;
  if (i < n) p[i] = 0.f;
}

__global__ void k_tanh_half(const float* __restrict__ w, float* __restrict__ m, int n) {
  int i = blockIdx.x * 256 + threadIdx.x;
  if (i < n) m[i] = tanhf(0.5f * w[i]);
}

// partial column sum: s[j] += sum_{i in [r0,rend)} (1 - m[i][j]^2); s zero-initialized
__global__ void k_colsum_part(const float* __restrict__ m, float* __restrict__ s,
                              int rows_per, int rows_total) {
  int j = threadIdx.x;
  int r0 = blockIdx.x * rows_per;
  int rend = min(r0 + rows_per, rows_total);
  float acc = 0.f;
  for (int i = r0; i < rend; ++i) {
    float v = m[i * 256 + j];
    acc = fmaf(-v, v, acc + 1.0f);
  }
  atomicAdd(&s[j], acc);
}

// layer 1: one block per output row r; thread j computes h1[r,j] over K=784
__global__ void k_layer1(const float* __restrict__ x, const float* __restrict__ m0,
                         const float* __restrict__ diagsig1, const float* __restrict__ th0,
                         float* __restrict__ x1bar, float* __restrict__ d1) {
  __shared__ float xr[784];
  int r = blockIdx.x, j = threadIdx.x;
  for (int p = j; p < 784; p += 256) xr[p] = x[r * 784 + p];
  __syncthreads();
  float acc = 0.f;
#pragma unroll 8
  for (int k = 0; k < 784; ++k) acc = fmaf(xr[k], m0[k * 256 + j], acc);
  float rs = rsqrtf(diagsig1[j]);
  float xb = tanhf(SQ2PI_F * (acc + th0[j]) * rs);
  x1bar[r * 256 + j] = xb;
  d1[r * 256 + j] = 1.f - xb * xb;
}

// layer-2 small pass: diagsig2 = d1 @ (m1*m1) + s1 ; h2 = x1bar @ m1 + th1
__global__ void k_layer2_small(const float* __restrict__ d1, const float* __restrict__ x1bar,
                               const float* __restrict__ m1, const float* __restrict__ s1,
                               const float* __restrict__ th1,
                               float* __restrict__ x2bar, float* __restrict__ c2,
                               float* __restrict__ d2p) {
  int r = blockIdx.x, i = threadIdx.x;
  float accd = 0.f, acch = 0.f;
  for (int j = 0; j < 256; ++j) {
    float mm = m1[j * 256 + i];
    accd = fmaf(d1[r * 256 + j] * mm, mm, accd);
    acch = fmaf(x1bar[r * 256 + j], mm, acch);
  }
  float rs = rsqrtf(accd + s1[i]);
  float xb = tanhf(SQ2PI_F * (acch + th1[i]) * rs);
  x2bar[r * 256 + i] = xb;
  float d = 1.f - xb * xb;
  c2[r * 256 + i] = d * rs;
  d2p[r * 256 + i] = d;
}

// layer-3 small pass: diagsig3[r,i] = sum_j m2[j,i]*t3[r,j,i] + s2[i]
__global__ void k_layer3_small(const float* __restrict__ t3, const float* __restrict__ m2,
                               const float* __restrict__ x2bar, const float* __restrict__ s2,
                               const float* __restrict__ th2,
                               float* __restrict__ x3bar, float* __restrict__ c3,
                               float* __restrict__ d3p) {
  int r = blockIdx.x, i = threadIdx.x;
  const float* t3b = t3 + (size_t)r * 65536;
  float accd = 0.f, acch = 0.f;
  for (int j = 0; j < 256; ++j) {
    float mm = m2[j * 256 + i];
    accd = fmaf(mm, t3b[j * 256 + i], accd);
    acch = fmaf(x2bar[r * 256 + j], mm, acch);
  }
  float rs = rsqrtf(accd + s2[i]);
  float xb = tanhf(SQ2PI_F * (acch + th2[i]) * rs);
  x3bar[r * 256 + i] = xb;
  float d = 1.f - xb * xb;
  c3[r * 256 + i] = d * rs;
  d3p[r * 256 + i] = d;
}

// final layer + log_softmax + loss + frac_correct. <<<1,256>>>, thread = row
__global__ void k_final(const float* __restrict__ x3bar, const float* __restrict__ mlast,
                        const float* __restrict__ thlast, const int* __restrict__ target,
                        float* __restrict__ hlast_out, float* __restrict__ logp_out,
                        float* __restrict__ loss_out, float* __restrict__ frac_out) {
  __shared__ float Wl[2560];
  __shared__ float red[256];
  int t = threadIdx.x;
  for (int p = t; p < 2560; p += 256) Wl[p] = mlast[p];
  __syncthreads();
  int r = t;
  float acc[10];
#pragma unroll
  for (int c = 0; c < 10; ++c) acc[c] = thlast[c];
  for (int j = 0; j < 256; ++j) {
    float xv = x3bar[r * 256 + j];
#pragma unroll
    for (int c = 0; c < 10; ++c) acc[c] = fmaf(xv, Wl[j * 10 + c], acc[c]);
  }
#pragma unroll
  for (int c = 0; c < 10; ++c) hlast_out[r * 10 + c] = acc[c];
  float mx = acc[0];
  int am = 0;
#pragma unroll
  for (int c = 1; c < 10; ++c)
    if (acc[c] > mx) { mx = acc[c]; am = c; }
  float se = 0.f;
#pragma unroll
  for (int c = 0; c < 10; ++c) se += expf(acc[c] - mx);
  float lse = logf(se);
#pragma unroll
  for (int c = 0; c < 10; ++c) logp_out[r * 10 + c] = acc[c] - mx - lse;
  int tg = target[r];
  float lossc = -(acc[tg] - mx - lse);
  float corr = (am == tg) ? 1.f : 0.f;
  red[t] = lossc;
  __syncthreads();
  for (int s = 128; s > 0; s >>= 1) {
    if (t < s) red[t] += red[t + s];
    __syncthreads();
  }
  if (t == 0) loss_out[0] = red[0] * (1.f / 256.f);
  __syncthreads();
  red[t] = corr;
  __syncthreads();
  for (int s = 128; s > 0; s >>= 1) {
    if (t < s) red[t] += red[t + s];
    __syncthreads();
  }
  if (t == 0) frac_out[0] = red[0] * (1.f / 256.f);
}

// ------------------------------------------------------------------
// batched fp32 GEMM, 128x128 tile, 8x8 per thread, 256 threads. All
// operands 256x256 row-major; A consumed as A^T (direct k-major staging).
// MODE 5: gram.  acc[r,c] = sum_k m1[k,r] * d1[b,k] * m1[k,c]
//         epilogue: xcov2 = SQ2PI*c2_r*c2_c*(acc + (r==c)*s1) + (r==c)*d2p
// MODE 6: t3.    A = xcov2[b] (symmetric -> read k-major), B = m2, plain store
// MODE 8: sigma3. acc[r,c] = sum_k m2[k,r]*t3[b,k,c]; epilogue like mode 5
// LDS rows padded to 132 floats; B-fragment split tx*4 / 64+tx*4 -> <=2-way
// bank aliasing (free). No min-occupancy clamp: acc must stay in VGPRs.
// ------------------------------------------------------------------
template <int MODE>
__global__ __launch_bounds__(256) void gemm_tile(
    const float* __restrict__ A, const float* __restrict__ B,
    const float* __restrict__ w, const float* __restrict__ v0,
    const float* __restrict__ v1, const float* __restrict__ v2,
    float* __restrict__ out0) {
  constexpr int BK = 16;
  __shared__ float As[BK][132];
  __shared__ float Bs[BK][132];

  const int tid = threadIdx.x;
  const int tx = tid & 15;
  const int ty = tid >> 4;
  const int b = blockIdx.z;
  const int r0 = blockIdx.y * 128;
  const int c0 = blockIdx.x * 128;

  const float* Ab = (MODE == 6) ? A + (size_t)b * 65536 : A;
  const float* Bb = (MODE == 8) ? B + (size_t)b * 65536 : B;

  const int kA = ty;         // staging k-row 0..15
  const int mA = tx * 8;     // staging col base

  float pa[8], pb[8], wv = 1.f;

  auto load_tile = [&](int kt) {
    const float* p = Ab + (size_t)(kt + kA) * 256 + r0 + mA;
    *(float4*)&pa[0] = *(const float4*)p;
    *(float4*)&pa[4] = *(const float4*)(p + 4);
    const float* q = Bb + (size_t)(kt + kA) * 256 + c0 + mA;
    *(float4*)&pb[0] = *(const float4*)q;
    *(float4*)&pb[4] = *(const float4*)(q + 4);
    if (MODE == 5) wv = w[b * 256 + kt + kA];
  };

  float acc[8][8];
#pragma unroll
  for (int i = 0; i < 8; ++i)
#pragma unroll
    for (int j = 0; j < 8; ++j) acc[i][j] = 0.f;

  load_tile(0);
  for (int t = 0; t < 16; ++t) {
    __syncthreads();
    *(float4*)&As[kA][mA] = *(float4*)&pa[0];
    *(float4*)&As[kA][mA + 4] = *(float4*)&pa[4];
    if (MODE == 5) {
#pragma unroll
      for (int e = 0; e < 8; ++e) pb[e] *= wv;
    }
    *(float4*)&Bs[kA][mA] = *(float4*)&pb[0];
    *(float4*)&Bs[kA][mA + 4] = *(float4*)&pb[4];
    __syncthreads();
    if (t + 1 < 16) load_tile((t + 1) * BK);
#pragma unroll
    for (int kk = 0; kk < BK; ++kk) {
      float af[8], bf[8];
      *(float4*)&af[0] = *(const float4*)&As[kk][ty * 8];
      *(float4*)&af[4] = *(const float4*)&As[kk][ty * 8 + 4];
      *(float4*)&bf[0] = *(const float4*)&Bs[kk][tx * 4];
      *(float4*)&bf[4] = *(const float4*)&Bs[kk][64 + tx * 4];
#pragma unroll
      for (int i = 0; i < 8; ++i)
#pragma unroll
        for (int j = 0; j < 8; ++j) acc[i][j] = fmaf(af[i], bf[j], acc[i][j]);
    }
  }

#pragma unroll
  for (int i = 0; i < 8; ++i) {
    const int r = r0 + ty * 8 + i;
    float ci = (MODE == 6) ? 0.f : v0[b * 256 + r];
#pragma unroll
    for (int h = 0; h < 2; ++h) {
      float row[4];
#pragma unroll
      for (int j = 0; j < 4; ++j) {
        const int c = c0 + h * 64 + tx * 4 + j;
        float g = acc[i][h * 4 + j];
        if (MODE == 6) {
          row[j] = g;
        } else {
          float cl = v0[b * 256 + c];
          if (r == c) g += v1[r];
          row[j] = SQ2PI_F * ci * cl * g + ((r == c) ? v2[b * 256 + c] : 0.f);
        }
      }
      size_t o = (size_t)b * 65536 + (size_t)r * 256 + c0 + h * 64 + tx * 4;
      *(float4*)&out0[o] = *(float4*)&row[0];
    }
  }
}

// ------------------------------------------------------------------

extern "C" void kernel_launch(void* const* d_in, const int* in_sizes, int n_in,
                              void* d_out, int out_size, void* d_ws, size_t ws_size,
                              hipStream_t stream) {
  const float* x = (const float*)d_in[0];
  const int* target = (const int*)d_in[1];
  const float* w0 = (const float*)d_in[2];
  const float* w1 = (const float*)d_in[3];
  const float* w2 = (const float*)d_in[4];
  const float* wlast = (const float*)d_in[5];
  const float* th0 = (const float*)d_in[6];
  const float* th1 = (const float*)d_in[7];
  const float* th2 = (const float*)d_in[8];
  const float* thlast = (const float*)d_in[9];

  float* W = (float*)d_ws;
  size_t o = 0;
  auto alloc = [&](size_t n) { float* p = W + o; o += n; return p; };
  float* m0 = alloc(200704);
  float* m1 = alloc(65536);
  float* m2 = alloc(65536);
  float* mlast = alloc(2560);
  float* diagsig1 = alloc(256);
  float* s1 = alloc(256);
  float* s2 = alloc(256);
  float* x1bar = alloc(65536);
  float* d1 = alloc(65536);
  float* x2bar = alloc(65536);
  float* c2 = alloc(65536);
  float* d2p = alloc(65536);
  float* x3bar = alloc(65536);
  float* c3 = alloc(65536);
  float* d3p = alloc(65536);
  o = (o + 63) & ~(size_t)63;
  float* bufA = alloc(16777216);  // xcov2 (and xcov3 in small-ws path)
  bool big_ws = (ws_size >= (o + 16777216 + 64) * sizeof(float));
  float* bufB = big_ws ? alloc(16777216) : nullptr;

  float* hlast = (float*)d_out;
  float* logp = hlast + 2560;
  float* xcov3_out = logp + 2560;
  float* loss = xcov3_out + 16777216;
  float* frac = loss + 1;

  float* t3 = big_ws ? bufB : xcov3_out;         // t3 scratch
  float* xcov3_dst = big_ws ? xcov3_out : bufA;  // where mode-8 writes

  // 0) zero the three colsum vectors (contiguous: diagsig1, s1, s2)
  k_zero<<<3, 256, 0, stream>>>(diagsig1, 768);

  // 1) m = tanh(w/2)
  k_tanh_half<<<784, 256, 0, stream>>>(w0, m0, 200704);
  k_tanh_half<<<256, 256, 0, stream>>>(w1, m1, 65536);
  k_tanh_half<<<256, 256, 0, stream>>>(w2, m2, 65536);
  k_tanh_half<<<10, 256, 0, stream>>>(wlast, mlast, 2560);

  // 2) column sums (parallel partials + atomics)
  k_colsum_part<<<7, 256, 0, stream>>>(m0, diagsig1, 112, 784);
  k_colsum_part<<<4, 256, 0, stream>>>(m1, s1, 64, 256);
  k_colsum_part<<<4, 256, 0, stream>>>(m2, s2, 64, 256);

  // 3) layer 1: x1bar, d1 (one block per row, K=784)
  k_layer1<<<256, 256, 0, stream>>>(x, m0, diagsig1, th0, x1bar, d1);

  // 4) layer 2 small: x2bar, c2, d2p
  k_layer2_small<<<256, 256, 0, stream>>>(d1, x1bar, m1, s1, th1, x2bar, c2, d2p);

  // 5) xcov2 (fused gram + epilogue)
  gemm_tile<5><<<dim3(2, 2, 256), 256, 0, stream>>>(m1, m1, d1, c2, s1, d2p, bufA);

  // 6) t3 = xcov2 @ m2 (xcov2 symmetric -> k-major read)
  gemm_tile<6><<<dim3(2, 2, 256), 256, 0, stream>>>(bufA, m2, nullptr, nullptr,
                                                    nullptr, nullptr, t3);

  // 7) layer 3 small: x3bar, c3, d3p
  k_layer3_small<<<256, 256, 0, stream>>>(t3, m2, x2bar, s2, th2, x3bar, c3, d3p);

  // 8) xcov3 (fused sigma3 + epilogue)
  gemm_tile<8><<<dim3(2, 2, 256), 256, 0, stream>>>(m2, t3, nullptr, c3, s2, d3p,
                                                    xcov3_dst);
  if (!big_ws) {
    hipMemcpyAsync(xcov3_out, bufA, (size_t)16777216 * sizeof(float),
                   hipMemcpyDeviceToDevice, stream);
  }

  // 9) final layer + softmax + loss + acc
  k_final<<<1, 256, 0, stream>>>(x3bar, mlast, thlast, target, hlast, logp, loss, frac);
}

// Round 3
// 321.750 us; speedup vs baseline: 6.7842x; 1.5892x over previous
//
#include <hip/hip_runtime.h>
#include <math.h>

#define SQ2PI_F 0.79788456f

typedef __attribute__((ext_vector_type(8))) short short8;
typedef __attribute__((ext_vector_type(4))) float f32x4;
typedef __attribute__((ext_vector_type(4))) unsigned short u16x4;

__device__ inline unsigned short bf16rne(float x) {
  unsigned int u = __float_as_uint(x);
  u += 0x7fffu + ((u >> 16) & 1u);
  return (unsigned short)(u >> 16);
}

// ------------------------------------------------------------------
// small kernels
// ------------------------------------------------------------------

__global__ void k_zero(float* __restrict__ p, int n) {
  int i = blockIdx.x * 256 + threadIdx.x;
  if (i < n) p[i] = 0.f;
}

__global__ void k_tanh_half(const float* __restrict__ w, float* __restrict__ m, int n) {
  int i = blockIdx.x * 256 + threadIdx.x;
  if (i < n) m[i] = tanhf(0.5f * w[i]);
}

// m1 = tanh(w/2) row-major + f32 transpose
__global__ void k_m1t(const float* __restrict__ w, float* __restrict__ m,
                      float* __restrict__ mt) {
  int j = blockIdx.x, i = threadIdx.x;
  float v = tanhf(0.5f * w[j * 256 + i]);
  m[j * 256 + i] = v;
  mt[i * 256 + j] = v;
}

// m2 = tanh(w/2) row-major f32 + bf16 transpose
__global__ void k_m2t(const float* __restrict__ w, float* __restrict__ m,
                      unsigned short* __restrict__ mth) {
  int j = blockIdx.x, i = threadIdx.x;
  float v = tanhf(0.5f * w[j * 256 + i]);
  m[j * 256 + i] = v;
  mth[i * 256 + j] = bf16rne(v);
}

// partial column sum: s[j] += sum_{i} (1 - m[i][j]^2); s zero-initialized
__global__ void k_colsum_part(const float* __restrict__ m, float* __restrict__ s,
                              int rows_per, int rows_total) {
  int j = threadIdx.x;
  int r0 = blockIdx.x * rows_per;
  int rend = min(r0 + rows_per, rows_total);
  float acc = 0.f;
  for (int i = r0; i < rend; ++i) {
    float v = m[i * 256 + j];
    acc = fmaf(-v, v, acc + 1.0f);
  }
  atomicAdd(&s[j], acc);
}

// Pt[r*256+c][k] = m1t[r][k] * m1t[c][k], bf16. grid 1024, block 256 (thread=k)
__global__ void k_makeP(const float* __restrict__ m1t, unsigned short* __restrict__ Pt) {
  int t = threadIdx.x, blk = blockIdx.x;
  int r = blk >> 2, cb = (blk & 3) * 64;
  float a = m1t[r * 256 + t];
#pragma unroll 4
  for (int q = 0; q < 64; ++q) {
    float v = a * m1t[(cb + q) * 256 + t];
    Pt[(size_t)(blk * 64 + q) * 256 + t] = bf16rne(v);
  }
}

// layer 1: block=row r, thread=col j, K=784. emits x1bar, d1 (f32) and d1_hi (bf16)
__global__ void k_layer1(const float* __restrict__ x, const float* __restrict__ m0,
                         const float* __restrict__ diagsig1, const float* __restrict__ th0,
                         float* __restrict__ x1bar, float* __restrict__ d1,
                         unsigned short* __restrict__ d1h) {
  __shared__ float xr[784];
  int r = blockIdx.x, j = threadIdx.x;
  for (int p = j; p < 784; p += 256) xr[p] = x[r * 784 + p];
  __syncthreads();
  float acc = 0.f;
#pragma unroll 8
  for (int k = 0; k < 784; ++k) acc = fmaf(xr[k], m0[k * 256 + j], acc);
  float rs = rsqrtf(diagsig1[j]);
  float xb = tanhf(SQ2PI_F * (acc + th0[j]) * rs);
  x1bar[r * 256 + j] = xb;
  float d = 1.f - xb * xb;
  d1[r * 256 + j] = d;
  d1h[r * 256 + j] = bf16rne(d);
}

// layer-2 small pass: diagsig2 = d1 @ (m1*m1) + s1 ; h2 = x1bar @ m1 + th1
__global__ void k_layer2_small(const float* __restrict__ d1, const float* __restrict__ x1bar,
                               const float* __restrict__ m1, const float* __restrict__ s1,
                               const float* __restrict__ th1,
                               float* __restrict__ x2bar, float* __restrict__ c2,
                               float* __restrict__ d2p) {
  int r = blockIdx.x, i = threadIdx.x;
  float accd = 0.f, acch = 0.f;
  for (int j = 0; j < 256; ++j) {
    float mm = m1[j * 256 + i];
    accd = fmaf(d1[r * 256 + j] * mm, mm, accd);
    acch = fmaf(x1bar[r * 256 + j], mm, acch);
  }
  float rs = rsqrtf(accd + s1[i]);
  float xb = tanhf(SQ2PI_F * (acch + th1[i]) * rs);
  x2bar[r * 256 + i] = xb;
  float d = 1.f - xb * xb;
  c2[r * 256 + i] = d * rs;
  d2p[r * 256 + i] = d;
}

// layer-3 small pass: diagsig3 pre-accumulated (atomics from mode-6 epilogue);
// h3 = x2bar @ m2 + th2 -> x3bar, c3, d3p
__global__ void k_layer3h(const float* __restrict__ dsig3, const float* __restrict__ s2,
                          const float* __restrict__ x2bar, const float* __restrict__ m2,
                          const float* __restrict__ th2,
                          float* __restrict__ x3bar, float* __restrict__ c3,
                          float* __restrict__ d3p) {
  int r = blockIdx.x, i = threadIdx.x;
  float acch = 0.f;
  for (int j = 0; j < 256; ++j)
    acch = fmaf(x2bar[r * 256 + j], m2[j * 256 + i], acch);
  float ds = dsig3[r * 256 + i] + s2[i];
  float rs = rsqrtf(ds);
  float xb = tanhf(SQ2PI_F * (acch + th2[i]) * rs);
  x3bar[r * 256 + i] = xb;
  float d = 1.f - xb * xb;
  c3[r * 256 + i] = d * rs;
  d3p[r * 256 + i] = d;
}

// final layer + log_softmax + loss + frac_correct. <<<1,256>>>, thread = row
__global__ void k_final(const float* __restrict__ x3bar, const float* __restrict__ mlast,
                        const float* __restrict__ thlast, const int* __restrict__ target,
                        float* __restrict__ hlast_out, float* __restrict__ logp_out,
                        float* __restrict__ loss_out, float* __restrict__ frac_out) {
  __shared__ float Wl[2560];
  __shared__ float red[256];
  int t = threadIdx.x;
  for (int p = t; p < 2560; p += 256) Wl[p] = mlast[p];
  __syncthreads();
  int r = t;
  float acc[10];
#pragma unroll
  for (int c = 0; c < 10; ++c) acc[c] = thlast[c];
  for (int j = 0; j < 256; ++j) {
    float xv = x3bar[r * 256 + j];
#pragma unroll
    for (int c = 0; c < 10; ++c) acc[c] = fmaf(xv, Wl[j * 10 + c], acc[c]);
  }
#pragma unroll
  for (int c = 0; c < 10; ++c) hlast_out[r * 10 + c] = acc[c];
  float mx = acc[0];
  int am = 0;
#pragma unroll
  for (int c = 1; c < 10; ++c)
    if (acc[c] > mx) { mx = acc[c]; am = c; }
  float se = 0.f;
#pragma unroll
  for (int c = 0; c < 10; ++c) se += expf(acc[c] - mx);
  float lse = logf(se);
#pragma unroll
  for (int c = 0; c < 10; ++c) logp_out[r * 10 + c] = acc[c] - mx - lse;
  int tg = target[r];
  float lossc = -(acc[tg] - mx - lse);
  float corr = (am == tg) ? 1.f : 0.f;
  red[t] = lossc;
  __syncthreads();
  for (int s = 128; s > 0; s >>= 1) {
    if (t < s) red[t] += red[t + s];
    __syncthreads();
  }
  if (t == 0) loss_out[0] = red[0] * (1.f / 256.f);
  __syncthreads();
  red[t] = corr;
  __syncthreads();
  for (int s = 128; s > 0; s >>= 1) {
    if (t < s) red[t] += red[t + s];
    __syncthreads();
  }
  if (t == 0) frac_out[0] = red[0] * (1.f / 256.f);
}

// ------------------------------------------------------------------
// MFMA GEMM, no LDS. block = 256 thr = 4 waves (2x2), block tile 128x128,
// wave tile 64x64 = 4x4 frags of 16x16, K=256 in 8 steps of 32.
// A-frag source [row][k] bf16 row-major; B-frag source [col][k] bf16.
// MODE 5: xcov2. A=Pt[rc][k], B=d1_hi[b][k]. out rows=rc, cols=b.
//         epilogue: xcov2_hi[b][r*256+c] (bf16, symmetric store).
// MODE 6: t3. A=xcov2_hi[b] (symmetric -> row-major ok), B=m2t_hi.
//         out[r][c]=t3[b][r][c]; store t3t_hi[b][c][r]; diagsig3 atomics.
// MODE 8: xcov3. A=m2t_hi, B=t3t_hi[b]. epilogue writes fp32 to d_out,
//         symmetric-transposed (float4 along r).
// ------------------------------------------------------------------
template <int MODE>
__global__ __launch_bounds__(256) void mfma_gemm(
    const unsigned short* __restrict__ Abf, const unsigned short* __restrict__ Bbf,
    const float* __restrict__ e0, const float* __restrict__ e1,
    const float* __restrict__ e2, float* __restrict__ outf,
    unsigned short* __restrict__ outh, float* __restrict__ dsig) {
  const int tid = threadIdx.x;
  const int l = tid & 63;
  const int w = tid >> 6;
  const int lr = l & 15, lk = l >> 4;
  const int wr = (w >> 1) * 64, wc = (w & 1) * 64;
  const int b = blockIdx.z;
  const int rowA = blockIdx.y * 128 + wr;
  const int colB = blockIdx.x * 128 + wc;

  size_t aoff[4], boff[4];
#pragma unroll
  for (int f = 0; f < 4; ++f) {
    size_t ab = (MODE == 6) ? ((size_t)b << 16) : 0;
    size_t bb = (MODE == 8) ? ((size_t)b << 16) : 0;
    aoff[f] = ab + (size_t)(rowA + f * 16 + lr) * 256 + (size_t)(lk * 8);
    boff[f] = bb + (size_t)(colB + f * 16 + lr) * 256 + (size_t)(lk * 8);
  }

  f32x4 acc[4][4];
#pragma unroll
  for (int i = 0; i < 4; ++i)
#pragma unroll
    for (int j = 0; j < 4; ++j) acc[i][j] = {0.f, 0.f, 0.f, 0.f};

#pragma unroll
  for (int kt = 0; kt < 8; ++kt) {
    short8 a[4], bq[4];
#pragma unroll
    for (int f = 0; f < 4; ++f) {
      a[f] = *(const short8*)(Abf + aoff[f] + kt * 32);
      bq[f] = *(const short8*)(Bbf + boff[f] + kt * 32);
    }
#pragma unroll
    for (int i = 0; i < 4; ++i)
#pragma unroll
      for (int j = 0; j < 4; ++j)
        acc[i][j] = __builtin_amdgcn_mfma_f32_16x16x32_bf16(a[i], bq[j], acc[i][j], 0, 0, 0);
  }

  if (MODE == 5) {
    const int r_f = blockIdx.y >> 1;                 // fixed r for this rc-tile
    const int cwave = (blockIdx.y & 1) * 128 + wr;   // c-coordinate base
    const float s1r = e1[r_f];
#pragma unroll
    for (int i = 0; i < 4; ++i) {
      int cb0 = cwave + i * 16 + lk * 4;
#pragma unroll
      for (int j = 0; j < 4; ++j) {
        int bb = colB + j * 16 + lr;                 // batch index
        float c2r = e0[bb * 256 + r_f];
        u16x4 st;
#pragma unroll
        for (int e = 0; e < 4; ++e) {
          int cc = cb0 + e;
          float g = acc[i][j][e];
          if (cc == r_f) g += s1r;
          float v = SQ2PI_F * c2r * e0[bb * 256 + cc] * g;
          if (cc == r_f) v += e2[bb * 256 + cc];
          st[e] = bf16rne(v);
        }
        *(u16x4*)(outh + ((size_t)bb << 16) + (size_t)r_f * 256 + cb0) = st;
      }
    }
  } else if (MODE == 6) {
    float dpart[4] = {0.f, 0.f, 0.f, 0.f};
#pragma unroll
    for (int i = 0; i < 4; ++i) {
      int rb = rowA + i * 16 + lk * 4;
#pragma unroll
      for (int j = 0; j < 4; ++j) {
        int cc = colB + j * 16 + lr;
        u16x4 st;
        float dp = 0.f;
#pragma unroll
        for (int e = 0; e < 4; ++e) {
          float v = acc[i][j][e];
          st[e] = bf16rne(v);
          dp = fmaf(e0[(rb + e) * 256 + cc], v, dp);  // m2[r][c] * t3[r][c]
        }
        dpart[j] += dp;
        *(u16x4*)(outh + ((size_t)b << 16) + (size_t)cc * 256 + rb) = st;
      }
    }
#pragma unroll
    for (int j = 0; j < 4; ++j) {
      float s = dpart[j];
      s += __shfl_xor(s, 16, 64);
      s += __shfl_xor(s, 32, 64);
      if (l < 16) atomicAdd(&dsig[b * 256 + colB + j * 16 + l], s);
    }
  } else {  // MODE 8
#pragma unroll
    for (int i = 0; i < 4; ++i) {
      int rb = rowA + i * 16 + lk * 4;
#pragma unroll
      for (int j = 0; j < 4; ++j) {
        int cc = colB + j * 16 + lr;
        float c3c = e0[b * 256 + cc];
        f32x4 st;
#pragma unroll
        for (int e = 0; e < 4; ++e) {
          int rr = rb + e;
          float g = acc[i][j][e];
          if (rr == cc) g += e1[rr];
          float v = SQ2PI_F * e0[b * 256 + rr] * c3c * g;
          if (rr == cc) v += e2[b * 256 + cc];
          st[e] = v;
        }
        *(f32x4*)(outf + ((size_t)b << 16) + (size_t)cc * 256 + rb) = st;
      }
    }
  }
}

// ------------------------------------------------------------------

extern "C" void kernel_launch(void* const* d_in, const int* in_sizes, int n_in,
                              void* d_out, int out_size, void* d_ws, size_t ws_size,
                              hipStream_t stream) {
  const float* x = (const float*)d_in[0];
  const int* target = (const int*)d_in[1];
  const float* w0 = (const float*)d_in[2];
  const float* w1 = (const float*)d_in[3];
  const float* w2 = (const float*)d_in[4];
  const float* wlast = (const float*)d_in[5];
  const float* th0 = (const float*)d_in[6];
  const float* th1 = (const float*)d_in[7];
  const float* th2 = (const float*)d_in[8];
  const float* thlast = (const float*)d_in[9];

  float* W = (float*)d_ws;
  size_t o = 0;
  auto alloc = [&](size_t n) { float* p = W + o; o += n; return p; };
  float* m0 = alloc(200704);
  float* m1 = alloc(65536);
  float* m2 = alloc(65536);
  float* m1t = alloc(65536);
  float* mlast = alloc(2560);
  float* diagsig1 = alloc(256);   // must stay contiguous:
  float* s1 = alloc(256);
  float* s2 = alloc(256);
  float* diagsig3 = alloc(65536);
  float* x1bar = alloc(65536);
  float* d1 = alloc(65536);
  float* x2bar = alloc(65536);
  float* c2 = alloc(65536);
  float* d2p = alloc(65536);
  float* x3bar = alloc(65536);
  float* c3 = alloc(65536);
  float* d3p = alloc(65536);
  unsigned short* d1h = (unsigned short*)alloc(32768);     // 65536 bf16
  unsigned short* m2th = (unsigned short*)alloc(32768);    // 65536 bf16
  unsigned short* PtT3 = (unsigned short*)alloc(8388608);  // 16.7M bf16: Pt then t3t

  float* hlast = (float*)d_out;
  float* logp = hlast + 2560;
  float* xcov3_out = logp + 2560;
  float* loss = xcov3_out + 16777216;
  float* frac = loss + 1;
  // xcov2_hi borrows the xcov3 output slot (33.5 MB of its 67 MB);
  // consumed by mode 6, overwritten by mode 8 afterwards.
  unsigned short* xcov2h = (unsigned short*)xcov3_out;

  // 0) zero diagsig1,s1,s2,diagsig3 (contiguous, 66304 floats)
  k_zero<<<260, 256, 0, stream>>>(diagsig1, 66304);

  // 1) means
  k_tanh_half<<<784, 256, 0, stream>>>(w0, m0, 200704);
  k_m1t<<<256, 256, 0, stream>>>(w1, m1, m1t);
  k_m2t<<<256, 256, 0, stream>>>(w2, m2, m2th);
  k_tanh_half<<<10, 256, 0, stream>>>(wlast, mlast, 2560);

  // 2) column sums
  k_colsum_part<<<7, 256, 0, stream>>>(m0, diagsig1, 112, 784);
  k_colsum_part<<<4, 256, 0, stream>>>(m1, s1, 64, 256);
  k_colsum_part<<<4, 256, 0, stream>>>(m2, s2, 64, 256);

  // 3) Pt[rc][k] = m1t[r][k]*m1t[c][k]
  k_makeP<<<1024, 256, 0, stream>>>(m1t, PtT3);

  // 4) layer 1
  k_layer1<<<256, 256, 0, stream>>>(x, m0, diagsig1, th0, x1bar, d1, d1h);

  // 5) layer 2 small
  k_layer2_small<<<256, 256, 0, stream>>>(d1, x1bar, m1, s1, th1, x2bar, c2, d2p);

  // 6) xcov2 = MFMA(Pt, d1) + epilogue -> bf16 (in d_out slot)
  mfma_gemm<5><<<dim3(2, 512, 1), 256, 0, stream>>>(PtT3, d1h, c2, s1, d2p,
                                                    nullptr, xcov2h, nullptr);

  // 7) t3t = MFMA(xcov2, m2t), transposed bf16 store + diagsig3 atomics
  mfma_gemm<6><<<dim3(2, 2, 256), 256, 0, stream>>>(xcov2h, m2th, m2, nullptr,
                                                    nullptr, nullptr, PtT3, diagsig3);

  // 8) layer 3 small (h3 + diagsig3 -> x3bar, c3, d3p)
  k_layer3h<<<256, 256, 0, stream>>>(diagsig3, s2, x2bar, m2, th2, x3bar, c3, d3p);

  // 9) xcov3 = MFMA(m2t, t3t) + epilogue -> fp32 d_out
  mfma_gemm<8><<<dim3(2, 2, 256), 256, 0, stream>>>(m2th, PtT3, c3, s2, d3p,
                                                    xcov3_out, nullptr, nullptr);

  // 10) final layer + softmax + loss + acc
  k_final<<<1, 256, 0, stream>>>(x3bar, mlast, thlast, target, hlast, logp, loss, frac);
}

// Round 4
// 286.817 us; speedup vs baseline: 7.6105x; 1.1218x over previous
//
#include <hip/hip_runtime.h>
#include <math.h>

#define SQ2PI_F 0.79788456f

typedef __attribute__((ext_vector_type(8))) short short8;
typedef __attribute__((ext_vector_type(4))) float f32x4;
typedef __attribute__((ext_vector_type(4))) unsigned short u16x4;

__device__ inline unsigned short bf16rne(float x) {
  unsigned int u = __float_as_uint(x);
  u += 0x7fffu + ((u >> 16) & 1u);
  return (unsigned short)(u >> 16);
}

// ------------------------------------------------------------------
// fused prep: means (+transposes), zero accumulators, zero loss/frac
// blocks [0,784) m0 | [784,1040) m1+m1t | [1040,1296) m2+m2th |
// [1296,1306) mlast | [1306,1566) zero 66304 floats at dsig1
// ------------------------------------------------------------------
__global__ void k_prep(const float* __restrict__ w0, const float* __restrict__ w1,
                       const float* __restrict__ w2, const float* __restrict__ wlast,
                       float* __restrict__ m0, float* __restrict__ m1,
                       float* __restrict__ m1t, float* __restrict__ m2,
                       unsigned short* __restrict__ m2th, float* __restrict__ mlast,
                       float* __restrict__ zbase, float* __restrict__ lf) {
  int b = blockIdx.x, t = threadIdx.x;
  if (b < 784) {
    int i = b * 256 + t;
    m0[i] = tanhf(0.5f * w0[i]);
  } else if (b < 1040) {
    int j = b - 784;
    float v = tanhf(0.5f * w1[j * 256 + t]);
    m1[j * 256 + t] = v;
    m1t[t * 256 + j] = v;
  } else if (b < 1296) {
    int j = b - 1040;
    float v = tanhf(0.5f * w2[j * 256 + t]);
    m2[j * 256 + t] = v;
    m2th[t * 256 + j] = bf16rne(v);
  } else if (b < 1306) {
    int i = (b - 1296) * 256 + t;
    if (i < 2560) mlast[i] = tanhf(0.5f * wlast[i]);
    if (b == 1296 && t < 2) lf[t] = 0.f;
  } else {
    int i = (b - 1306) * 256 + t;
    if (i < 66304) zbase[i] = 0.f;
  }
}

// fused column sums: blocks 0..6 m0(112 rows) | 7..10 m1(64) | 11..14 m2(64)
__global__ void k_colsums(const float* __restrict__ m0, const float* __restrict__ m1,
                          const float* __restrict__ m2, float* __restrict__ dsig1,
                          float* __restrict__ s1, float* __restrict__ s2) {
  int b = blockIdx.x, j = threadIdx.x;
  const float* src;
  float* dst;
  int r0, rn;
  if (b < 7) { src = m0; dst = dsig1; r0 = b * 112; rn = r0 + 112; }
  else if (b < 11) { src = m1; dst = s1; r0 = (b - 7) * 64; rn = r0 + 64; }
  else { src = m2; dst = s2; r0 = (b - 11) * 64; rn = r0 + 64; }
  float acc = 0.f;
  for (int i = r0; i < rn; ++i) {
    float v = src[i * 256 + j];
    acc = fmaf(-v, v, acc + 1.0f);
  }
  atomicAdd(&dst[j], acc);
}

// Pt[r*256+c][k] = m1t[r][k] * m1t[c][k], bf16. grid 1024, block 256 (thread=k)
__global__ void k_makeP(const float* __restrict__ m1t, unsigned short* __restrict__ Pt) {
  int t = threadIdx.x, blk = blockIdx.x;
  int r = blk >> 2, cb = (blk & 3) * 64;
  float a = m1t[r * 256 + t];
#pragma unroll 4
  for (int q = 0; q < 64; ++q) {
    float v = a * m1t[(cb + q) * 256 + t];
    Pt[(size_t)(blk * 64 + q) * 256 + t] = bf16rne(v);
  }
}

// layer 1: block=row r, thread=col j, K=784
__global__ void k_layer1(const float* __restrict__ x, const float* __restrict__ m0,
                         const float* __restrict__ diagsig1, const float* __restrict__ th0,
                         float* __restrict__ x1bar, float* __restrict__ d1,
                         unsigned short* __restrict__ d1h) {
  __shared__ float xr[784];
  int r = blockIdx.x, j = threadIdx.x;
  for (int p = j; p < 784; p += 256) xr[p] = x[r * 784 + p];
  __syncthreads();
  float acc = 0.f;
#pragma unroll 8
  for (int k = 0; k < 784; ++k) acc = fmaf(xr[k], m0[k * 256 + j], acc);
  float rs = rsqrtf(diagsig1[j]);
  float xb = tanhf(SQ2PI_F * (acc + th0[j]) * rs);
  x1bar[r * 256 + j] = xb;
  float d = 1.f - xb * xb;
  d1[r * 256 + j] = d;
  d1h[r * 256 + j] = bf16rne(d);
}

// layer-2 small pass
__global__ void k_layer2_small(const float* __restrict__ d1, const float* __restrict__ x1bar,
                               const float* __restrict__ m1, const float* __restrict__ s1,
                               const float* __restrict__ th1,
                               float* __restrict__ x2bar, float* __restrict__ c2,
                               float* __restrict__ d2p) {
  int r = blockIdx.x, i = threadIdx.x;
  float accd = 0.f, acch = 0.f;
  for (int j = 0; j < 256; ++j) {
    float mm = m1[j * 256 + i];
    accd = fmaf(d1[r * 256 + j] * mm, mm, accd);
    acch = fmaf(x1bar[r * 256 + j], mm, acch);
  }
  float rs = rsqrtf(accd + s1[i]);
  float xb = tanhf(SQ2PI_F * (acch + th1[i]) * rs);
  x2bar[r * 256 + i] = xb;
  float d = 1.f - xb * xb;
  c2[r * 256 + i] = d * rs;
  d2p[r * 256 + i] = d;
}

// layer-3 small pass (diagsig3 pre-accumulated by mode-6 epilogue atomics)
__global__ void k_layer3h(const float* __restrict__ dsig3, const float* __restrict__ s2,
                          const float* __restrict__ x2bar, const float* __restrict__ m2,
                          const float* __restrict__ th2,
                          float* __restrict__ x3bar, float* __restrict__ c3,
                          float* __restrict__ d3p) {
  int r = blockIdx.x, i = threadIdx.x;
  float acch = 0.f;
  for (int j = 0; j < 256; ++j)
    acch = fmaf(x2bar[r * 256 + j], m2[j * 256 + i], acch);
  float ds = dsig3[r * 256 + i] + s2[i];
  float rs = rsqrtf(ds);
  float xb = tanhf(SQ2PI_F * (acch + th2[i]) * rs);
  x3bar[r * 256 + i] = xb;
  float d = 1.f - xb * xb;
  c3[r * 256 + i] = d * rs;
  d3p[r * 256 + i] = d;
}

// final layer + log_softmax + loss + frac_correct. grid 4 x block 64 (one wave),
// thread = row. loss/frac accumulated via atomicAdd (zeroed in prep).
__global__ void k_final4(const float* __restrict__ x3bar, const float* __restrict__ mlast,
                         const float* __restrict__ thlast, const int* __restrict__ target,
                         float* __restrict__ hlast_out, float* __restrict__ logp_out,
                         float* __restrict__ loss_out, float* __restrict__ frac_out) {
  __shared__ float Wl[2560];
  int t = threadIdx.x;
  int r = blockIdx.x * 64 + t;
  for (int p = t; p < 2560; p += 64) Wl[p] = mlast[p];
  __syncthreads();
  float acc[10];
#pragma unroll
  for (int c = 0; c < 10; ++c) acc[c] = thlast[c];
  for (int j = 0; j < 256; ++j) {
    float xv = x3bar[r * 256 + j];
#pragma unroll
    for (int c = 0; c < 10; ++c) acc[c] = fmaf(xv, Wl[j * 10 + c], acc[c]);
  }
#pragma unroll
  for (int c = 0; c < 10; ++c) hlast_out[r * 10 + c] = acc[c];
  float mx = acc[0];
  int am = 0;
#pragma unroll
  for (int c = 1; c < 10; ++c)
    if (acc[c] > mx) { mx = acc[c]; am = c; }
  float se = 0.f;
#pragma unroll
  for (int c = 0; c < 10; ++c) se += expf(acc[c] - mx);
  float lse = logf(se);
#pragma unroll
  for (int c = 0; c < 10; ++c) logp_out[r * 10 + c] = acc[c] - mx - lse;
  int tg = target[r];
  float lossc = -(acc[tg] - mx - lse) * (1.f / 256.f);
  float corr = (am == tg) ? (1.f / 256.f) : 0.f;
#pragma unroll
  for (int off = 32; off > 0; off >>= 1) {
    lossc += __shfl_down(lossc, off);
    corr += __shfl_down(corr, off);
  }
  if (t == 0) {
    atomicAdd(loss_out, lossc);
    atomicAdd(frac_out, corr);
  }
}

// ------------------------------------------------------------------
// MFMA GEMM, no LDS, depth-2 register pipeline. block = 256 thr = 4 waves
// (2x2), block tile 128x128, wave tile 64x64 = 4x4 frags of 16x16, K=256.
// A-frag source [row][k] bf16; B-frag source [col][k] bf16.
// MODE 5: xcov2. A=Pt[rc][k], B=d1_hi[b][k] -> bf16 xcov2_hi (symmetric).
// MODE 6: t3. A=xcov2_hi[b], B=m2t_hi -> t3t_hi[b][c][r] + diagsig3 atomics.
// MODE 8: xcov3. A=m2t_hi, B=t3t_hi[b] -> fp32 d_out (symmetric-transposed).
// __launch_bounds__(256,2): VGPR budget 256 so acc(64) + two 32-reg load
// stages stay resident -> batched loads, counted vmcnt, latency hidden.
// ------------------------------------------------------------------
template <int MODE>
__global__ __launch_bounds__(256, 2) void mfma_gemm(
    const unsigned short* __restrict__ Abf, const unsigned short* __restrict__ Bbf,
    const float* __restrict__ e0, const float* __restrict__ e1,
    const float* __restrict__ e2, float* __restrict__ outf,
    unsigned short* __restrict__ outh, float* __restrict__ dsig) {
  const int tid = threadIdx.x;
  const int l = tid & 63;
  const int w = tid >> 6;
  const int lr = l & 15, lk = l >> 4;
  const int wr = (w >> 1) * 64, wc = (w & 1) * 64;
  const int b = blockIdx.z;
  const int rowA = blockIdx.y * 128 + wr;
  const int colB = blockIdx.x * 128 + wc;

  const unsigned short* ap[4];
  const unsigned short* bp[4];
#pragma unroll
  for (int f = 0; f < 4; ++f) {
    size_t ab = (MODE == 6) ? ((size_t)b << 16) : 0;
    size_t bb = (MODE == 8) ? ((size_t)b << 16) : 0;
    ap[f] = Abf + ab + (size_t)(rowA + f * 16 + lr) * 256 + (size_t)(lk * 8);
    bp[f] = Bbf + bb + (size_t)(colB + f * 16 + lr) * 256 + (size_t)(lk * 8);
  }

  f32x4 acc[4][4];
#pragma unroll
  for (int i = 0; i < 4; ++i)
#pragma unroll
    for (int j = 0; j < 4; ++j) acc[i][j] = {0.f, 0.f, 0.f, 0.f};

  short8 a0[4], b0[4], a1[4], b1[4];

#define LOADST(ar, br, kt)                              \
  {                                                     \
    _Pragma("unroll") for (int f = 0; f < 4; ++f) {     \
      ar[f] = *(const short8*)(ap[f] + (kt) * 32);      \
      br[f] = *(const short8*)(bp[f] + (kt) * 32);      \
    }                                                   \
  }
#define MMST(ar, br)                                                                  \
  {                                                                                   \
    _Pragma("unroll") for (int i = 0; i < 4; ++i) _Pragma("unroll")                   \
        for (int j = 0; j < 4; ++j) acc[i][j] =                                       \
            __builtin_amdgcn_mfma_f32_16x16x32_bf16(ar[i], br[j], acc[i][j], 0, 0, 0); \
  }

  LOADST(a0, b0, 0)
#pragma unroll
  for (int kt = 0; kt < 8; kt += 2) {
    if (kt + 1 < 8) LOADST(a1, b1, kt + 1)
    MMST(a0, b0)
    if (kt + 2 < 8) LOADST(a0, b0, kt + 2)
    MMST(a1, b1)
  }
#undef LOADST
#undef MMST

  if (MODE == 5) {
    const int r_f = blockIdx.y >> 1;                // fixed r for this rc-tile
    const int cwave = (blockIdx.y & 1) * 128 + wr;  // c-coordinate base
    const float s1r = e1[r_f];
#pragma unroll
    for (int i = 0; i < 4; ++i) {
      int cb0 = cwave + i * 16 + lk * 4;
#pragma unroll
      for (int j = 0; j < 4; ++j) {
        int bb = colB + j * 16 + lr;  // batch index
        float c2r = e0[bb * 256 + r_f];
        u16x4 st;
#pragma unroll
        for (int e = 0; e < 4; ++e) {
          int cc = cb0 + e;
          float g = acc[i][j][e];
          if (cc == r_f) g += s1r;
          float v = SQ2PI_F * c2r * e0[bb * 256 + cc] * g;
          if (cc == r_f) v += e2[bb * 256 + cc];
          st[e] = bf16rne(v);
        }
        *(u16x4*)(outh + ((size_t)bb << 16) + (size_t)r_f * 256 + cb0) = st;
      }
    }
  } else if (MODE == 6) {
    float dpart[4] = {0.f, 0.f, 0.f, 0.f};
#pragma unroll
    for (int i = 0; i < 4; ++i) {
      int rb = rowA + i * 16 + lk * 4;
#pragma unroll
      for (int j = 0; j < 4; ++j) {
        int cc = colB + j * 16 + lr;
        u16x4 st;
        float dp = 0.f;
#pragma unroll
        for (int e = 0; e < 4; ++e) {
          float v = acc[i][j][e];
          st[e] = bf16rne(v);
          dp = fmaf(e0[(rb + e) * 256 + cc], v, dp);  // m2[r][c] * t3[r][c]
        }
        dpart[j] += dp;
        *(u16x4*)(outh + ((size_t)b << 16) + (size_t)cc * 256 + rb) = st;
      }
    }
#pragma unroll
    for (int j = 0; j < 4; ++j) {
      float s = dpart[j];
      s += __shfl_xor(s, 16, 64);
      s += __shfl_xor(s, 32, 64);
      if (l < 16) atomicAdd(&dsig[b * 256 + colB + j * 16 + l], s);
    }
  } else {  // MODE 8
#pragma unroll
    for (int i = 0; i < 4; ++i) {
      int rb = rowA + i * 16 + lk * 4;
#pragma unroll
      for (int j = 0; j < 4; ++j) {
        int cc = colB + j * 16 + lr;
        float c3c = e0[b * 256 + cc];
        f32x4 st;
#pragma unroll
        for (int e = 0; e < 4; ++e) {
          int rr = rb + e;
          float g = acc[i][j][e];
          if (rr == cc) g += e1[rr];
          float v = SQ2PI_F * e0[b * 256 + rr] * c3c * g;
          if (rr == cc) v += e2[b * 256 + cc];
          st[e] = v;
        }
        *(f32x4*)(outf + ((size_t)b << 16) + (size_t)cc * 256 + rb) = st;
      }
    }
  }
}

// ------------------------------------------------------------------

extern "C" void kernel_launch(void* const* d_in, const int* in_sizes, int n_in,
                              void* d_out, int out_size, void* d_ws, size_t ws_size,
                              hipStream_t stream) {
  const float* x = (const float*)d_in[0];
  const int* target = (const int*)d_in[1];
  const float* w0 = (const float*)d_in[2];
  const float* w1 = (const float*)d_in[3];
  const float* w2 = (const float*)d_in[4];
  const float* wlast = (const float*)d_in[5];
  const float* th0 = (const float*)d_in[6];
  const float* th1 = (const float*)d_in[7];
  const float* th2 = (const float*)d_in[8];
  const float* thlast = (const float*)d_in[9];

  float* W = (float*)d_ws;
  size_t o = 0;
  auto alloc = [&](size_t n) { float* p = W + o; o += n; return p; };
  float* m0 = alloc(200704);
  float* m1 = alloc(65536);
  float* m2 = alloc(65536);
  float* m1t = alloc(65536);
  float* mlast = alloc(2560);
  float* diagsig1 = alloc(256);  // zero-block start (66304 floats)
  float* s1 = alloc(256);
  float* s2 = alloc(256);
  float* diagsig3 = alloc(65536);
  float* x1bar = alloc(65536);
  float* d1 = alloc(65536);
  float* x2bar = alloc(65536);
  float* c2 = alloc(65536);
  float* d2p = alloc(65536);
  float* x3bar = alloc(65536);
  float* c3 = alloc(65536);
  float* d3p = alloc(65536);
  unsigned short* d1h = (unsigned short*)alloc(32768);     // 65536 bf16
  unsigned short* m2th = (unsigned short*)alloc(32768);    // 65536 bf16
  unsigned short* PtT3 = (unsigned short*)alloc(8388608);  // Pt then t3t (bf16)

  float* hlast = (float*)d_out;
  float* logp = hlast + 2560;
  float* xcov3_out = logp + 2560;
  float* loss = xcov3_out + 16777216;
  float* frac = loss + 1;
  // xcov2_hi borrows the xcov3 output slot; consumed by mode 6, then overwritten.
  unsigned short* xcov2h = (unsigned short*)xcov3_out;

  // 1) prep: all means/transposes + zero dsig1,s1,s2,dsig3 + zero loss/frac
  k_prep<<<1566, 256, 0, stream>>>(w0, w1, w2, wlast, m0, m1, m1t, m2, m2th,
                                   mlast, diagsig1, loss);

  // 2) column sums (fused)
  k_colsums<<<15, 256, 0, stream>>>(m0, m1, m2, diagsig1, s1, s2);

  // 3) Pt[rc][k] = m1t[r][k]*m1t[c][k]
  k_makeP<<<1024, 256, 0, stream>>>(m1t, PtT3);

  // 4) layer 1
  k_layer1<<<256, 256, 0, stream>>>(x, m0, diagsig1, th0, x1bar, d1, d1h);

  // 5) layer 2 small
  k_layer2_small<<<256, 256, 0, stream>>>(d1, x1bar, m1, s1, th1, x2bar, c2, d2p);

  // 6) xcov2 = MFMA(Pt, d1) + epilogue -> bf16 (in d_out slot)
  mfma_gemm<5><<<dim3(2, 512, 1), 256, 0, stream>>>(PtT3, d1h, c2, s1, d2p,
                                                    nullptr, xcov2h, nullptr);

  // 7) t3t = MFMA(xcov2, m2t), transposed bf16 store + diagsig3 atomics
  mfma_gemm<6><<<dim3(2, 2, 256), 256, 0, stream>>>(xcov2h, m2th, m2, nullptr,
                                                    nullptr, nullptr, PtT3, diagsig3);

  // 8) layer 3 small (h3 + diagsig3 -> x3bar, c3, d3p)
  k_layer3h<<<256, 256, 0, stream>>>(diagsig3, s2, x2bar, m2, th2, x3bar, c3, d3p);

  // 9) xcov3 = MFMA(m2t, t3t) + epilogue -> fp32 d_out
  mfma_gemm<8><<<dim3(2, 2, 256), 256, 0, stream>>>(m2th, PtT3, c3, s2, d3p,
                                                    xcov3_out, nullptr, nullptr);

  // 10) final layer + softmax + loss + acc (4 blocks, atomic reduce)
  k_final4<<<4, 64, 0, stream>>>(x3bar, mlast, thlast, target, hlast, logp, loss, frac);
}

// Round 5
// 225.044 us; speedup vs baseline: 9.6995x; 1.2745x over previous
//
#include <hip/hip_runtime.h>
#include <math.h>

#define SQ2PI_F 0.79788456f

typedef __attribute__((ext_vector_type(8))) short short8;
typedef __attribute__((ext_vector_type(4))) float f32x4;
typedef __attribute__((ext_vector_type(4))) unsigned short u16x4;

typedef __attribute__((address_space(1))) unsigned int gas_u32;
typedef __attribute__((address_space(3))) unsigned int las_u32;

__device__ inline unsigned short bf16rne(float x) {
  unsigned int u = __float_as_uint(x);
  u += 0x7fffu + ((u >> 16) & 1u);
  return (unsigned short)(u >> 16);
}

// ------------------------------------------------------------------
// fused prep: means (+transposes), zero accumulators, zero loss/frac
// ------------------------------------------------------------------
__global__ void k_prep(const float* __restrict__ w0, const float* __restrict__ w1,
                       const float* __restrict__ w2, const float* __restrict__ wlast,
                       float* __restrict__ m0, float* __restrict__ m1,
                       float* __restrict__ m1t, float* __restrict__ m2,
                       unsigned short* __restrict__ m2th, float* __restrict__ mlast,
                       float* __restrict__ zbase, float* __restrict__ lf) {
  int b = blockIdx.x, t = threadIdx.x;
  if (b < 784) {
    int i = b * 256 + t;
    m0[i] = tanhf(0.5f * w0[i]);
  } else if (b < 1040) {
    int j = b - 784;
    float v = tanhf(0.5f * w1[j * 256 + t]);
    m1[j * 256 + t] = v;
    m1t[t * 256 + j] = v;
  } else if (b < 1296) {
    int j = b - 1040;
    float v = tanhf(0.5f * w2[j * 256 + t]);
    m2[j * 256 + t] = v;
    m2th[t * 256 + j] = bf16rne(v);
  } else if (b < 1306) {
    int i = (b - 1296) * 256 + t;
    if (i < 2560) mlast[i] = tanhf(0.5f * wlast[i]);
    if (b == 1296 && t < 2) lf[t] = 0.f;
  } else {
    int i = (b - 1306) * 256 + t;
    if (i < 66304) zbase[i] = 0.f;
  }
}

// fused column sums: blocks 0..6 m0(112 rows) | 7..10 m1(64) | 11..14 m2(64)
__global__ void k_colsums(const float* __restrict__ m0, const float* __restrict__ m1,
                          const float* __restrict__ m2, float* __restrict__ dsig1,
                          float* __restrict__ s1, float* __restrict__ s2) {
  int b = blockIdx.x, j = threadIdx.x;
  const float* src;
  float* dst;
  int r0, rn;
  if (b < 7) { src = m0; dst = dsig1; r0 = b * 112; rn = r0 + 112; }
  else if (b < 11) { src = m1; dst = s1; r0 = (b - 7) * 64; rn = r0 + 64; }
  else { src = m2; dst = s2; r0 = (b - 11) * 64; rn = r0 + 64; }
  float acc = 0.f;
  for (int i = r0; i < rn; ++i) {
    float v = src[i * 256 + j];
    acc = fmaf(-v, v, acc + 1.0f);
  }
  atomicAdd(&dst[j], acc);
}

// Pt[r*256+c][k] = m1t[r][k] * m1t[c][k], bf16. grid 1024, block 256 (thread=k)
__global__ void k_makeP(const float* __restrict__ m1t, unsigned short* __restrict__ Pt) {
  int t = threadIdx.x, blk = blockIdx.x;
  int r = blk >> 2, cb = (blk & 3) * 64;
  float a = m1t[r * 256 + t];
#pragma unroll 4
  for (int q = 0; q < 64; ++q) {
    float v = a * m1t[(cb + q) * 256 + t];
    Pt[(size_t)(blk * 64 + q) * 256 + t] = bf16rne(v);
  }
}

// layer 1: block=row r, thread=col j, K=784
__global__ void k_layer1(const float* __restrict__ x, const float* __restrict__ m0,
                         const float* __restrict__ diagsig1, const float* __restrict__ th0,
                         float* __restrict__ x1bar, float* __restrict__ d1,
                         unsigned short* __restrict__ d1h) {
  __shared__ float xr[784];
  int r = blockIdx.x, j = threadIdx.x;
  for (int p = j; p < 784; p += 256) xr[p] = x[r * 784 + p];
  __syncthreads();
  float acc = 0.f;
#pragma unroll 8
  for (int k = 0; k < 784; ++k) acc = fmaf(xr[k], m0[k * 256 + j], acc);
  float rs = rsqrtf(diagsig1[j]);
  float xb = tanhf(SQ2PI_F * (acc + th0[j]) * rs);
  x1bar[r * 256 + j] = xb;
  float d = 1.f - xb * xb;
  d1[r * 256 + j] = d;
  d1h[r * 256 + j] = bf16rne(d);
}

// layer-2 small pass
__global__ void k_layer2_small(const float* __restrict__ d1, const float* __restrict__ x1bar,
                               const float* __restrict__ m1, const float* __restrict__ s1,
                               const float* __restrict__ th1,
                               float* __restrict__ x2bar, float* __restrict__ c2,
                               float* __restrict__ d2p) {
  int r = blockIdx.x, i = threadIdx.x;
  float accd = 0.f, acch = 0.f;
  for (int j = 0; j < 256; ++j) {
    float mm = m1[j * 256 + i];
    accd = fmaf(d1[r * 256 + j] * mm, mm, accd);
    acch = fmaf(x1bar[r * 256 + j], mm, acch);
  }
  float rs = rsqrtf(accd + s1[i]);
  float xb = tanhf(SQ2PI_F * (acch + th1[i]) * rs);
  x2bar[r * 256 + i] = xb;
  float d = 1.f - xb * xb;
  c2[r * 256 + i] = d * rs;
  d2p[r * 256 + i] = d;
}

// layer-3 small pass (diagsig3 pre-accumulated by mode-6 epilogue atomics)
__global__ void k_layer3h(const float* __restrict__ dsig3, const float* __restrict__ s2,
                          const float* __restrict__ x2bar, const float* __restrict__ m2,
                          const float* __restrict__ th2,
                          float* __restrict__ x3bar, float* __restrict__ c3,
                          float* __restrict__ d3p) {
  int r = blockIdx.x, i = threadIdx.x;
  float acch = 0.f;
  for (int j = 0; j < 256; ++j)
    acch = fmaf(x2bar[r * 256 + j], m2[j * 256 + i], acch);
  float ds = dsig3[r * 256 + i] + s2[i];
  float rs = rsqrtf(ds);
  float xb = tanhf(SQ2PI_F * (acch + th2[i]) * rs);
  x3bar[r * 256 + i] = xb;
  float d = 1.f - xb * xb;
  c3[r * 256 + i] = d * rs;
  d3p[r * 256 + i] = d;
}

// final layer + log_softmax + loss + frac_correct. grid 4 x block 64
__global__ void k_final4(const float* __restrict__ x3bar, const float* __restrict__ mlast,
                         const float* __restrict__ thlast, const int* __restrict__ target,
                         float* __restrict__ hlast_out, float* __restrict__ logp_out,
                         float* __restrict__ loss_out, float* __restrict__ frac_out) {
  __shared__ float Wl[2560];
  int t = threadIdx.x;
  int r = blockIdx.x * 64 + t;
  for (int p = t; p < 2560; p += 64) Wl[p] = mlast[p];
  __syncthreads();
  float acc[10];
#pragma unroll
  for (int c = 0; c < 10; ++c) acc[c] = thlast[c];
  for (int j = 0; j < 256; ++j) {
    float xv = x3bar[r * 256 + j];
#pragma unroll
    for (int c = 0; c < 10; ++c) acc[c] = fmaf(xv, Wl[j * 10 + c], acc[c]);
  }
#pragma unroll
  for (int c = 0; c < 10; ++c) hlast_out[r * 10 + c] = acc[c];
  float mx = acc[0];
  int am = 0;
#pragma unroll
  for (int c = 1; c < 10; ++c)
    if (acc[c] > mx) { mx = acc[c]; am = c; }
  float se = 0.f;
#pragma unroll
  for (int c = 0; c < 10; ++c) se += expf(acc[c] - mx);
  float lse = logf(se);
#pragma unroll
  for (int c = 0; c < 10; ++c) logp_out[r * 10 + c] = acc[c] - mx - lse;
  int tg = target[r];
  float lossc = -(acc[tg] - mx - lse) * (1.f / 256.f);
  float corr = (am == tg) ? (1.f / 256.f) : 0.f;
#pragma unroll
  for (int off = 32; off > 0; off >>= 1) {
    lossc += __shfl_down(lossc, off);
    corr += __shfl_down(corr, off);
  }
  if (t == 0) {
    atomicAdd(loss_out, lossc);
    atomicAdd(frac_out, corr);
  }
}

// ------------------------------------------------------------------
// MFMA GEMM with global_load_lds double-buffered staging (m97 recipe).
// block = 256 thr = 4 waves (2x2), tile 128x128, BK=64, K=256 -> 4 stages.
// LDS: As/Bs[2][128][64] bf16 = 64KB (2 blocks/CU). Staging dest is LINEAR
// (wave-uniform base + lane*16B, per m104); the XOR swizzle (chunk ^= row&7)
// is applied on the GLOBAL SOURCE address (rule 21) and re-applied on the
// ds_read side, so ds_read_b128 across lr=0..15 spreads over 8 chunk slots
// (<=2-way bank aliasing, free).
// A-frag source [row][k] bf16; B-frag source [col][k] bf16 (NT GEMM).
// MODE 5: xcov2. A=Pt[rc][k], B=d1_hi[b][k] -> bf16 xcov2_hi (symmetric).
// MODE 6: t3. A=xcov2_hi[b], B=m2t_hi -> t3t_hi[b][c][r] + diagsig3 atomics.
// MODE 8: xcov3. A=m2t_hi, B=t3t_hi[b] -> fp32 d_out (symmetric-transposed).
// ------------------------------------------------------------------
template <int MODE>
__global__ __launch_bounds__(256, 2) void mfma_gemm(
    const unsigned short* __restrict__ Abf, const unsigned short* __restrict__ Bbf,
    const float* __restrict__ e0, const float* __restrict__ e1,
    const float* __restrict__ e2, float* __restrict__ outf,
    unsigned short* __restrict__ outh, float* __restrict__ dsig) {
  __shared__ __align__(16) unsigned short As[2][8192];
  __shared__ __align__(16) unsigned short Bs[2][8192];

  const int tid = threadIdx.x;
  const int l = tid & 63;
  const int w = tid >> 6;
  const int lr = l & 15, lk = l >> 4;
  const int wr = (w >> 1) * 64, wc = (w & 1) * 64;
  const int b = blockIdx.z;
  const int rowA = blockIdx.y * 128 + wr;
  const int colB = blockIdx.x * 128 + wc;

  const unsigned short* Ab = Abf + ((MODE == 6) ? ((size_t)b << 16) : (size_t)0) +
                             (size_t)blockIdx.y * 128 * 256;
  const unsigned short* Bb = Bbf + ((MODE == 8) ? ((size_t)b << 16) : (size_t)0) +
                             (size_t)blockIdx.x * 128 * 256;

  const int lr8 = l >> 3;               // staging sub-row 0..7
  const int lch = (l & 7) ^ lr8;        // inverse-swizzled source chunk

  // stage one 128x64 bf16 tile: 4 global_load_lds x16B per lane
  auto stage = [&](const unsigned short* g, unsigned short* ld) {
#pragma unroll
    for (int q = 0; q < 4; ++q) {
      int row = q * 32 + w * 8 + lr8;
      const unsigned short* src = g + (size_t)row * 256 + lch * 8;
      unsigned short* dst = ld + (q * 32 + w * 8) * 64;  // wave-uniform, +lane*16B by HW
      __builtin_amdgcn_global_load_lds((const gas_u32*)src, (las_u32*)dst, 16, 0, 0);
    }
  };

  f32x4 acc[4][4];
#pragma unroll
  for (int i = 0; i < 4; ++i)
#pragma unroll
    for (int j = 0; j < 4; ++j) acc[i][j] = {0.f, 0.f, 0.f, 0.f};

  auto compute = [&](const unsigned short* lA, const unsigned short* lB) {
#pragma unroll
    for (int kt = 0; kt < 2; ++kt) {
      short8 a[4], bq[4];
#pragma unroll
      for (int f = 0; f < 4; ++f) {
        int ra = wr + f * 16 + lr;
        a[f] = *(const short8*)(lA + ra * 64 + (((kt * 4 + lk) ^ (ra & 7)) << 3));
        int rb = wc + f * 16 + lr;
        bq[f] = *(const short8*)(lB + rb * 64 + (((kt * 4 + lk) ^ (rb & 7)) << 3));
      }
#pragma unroll
      for (int i = 0; i < 4; ++i)
#pragma unroll
        for (int j = 0; j < 4; ++j)
          acc[i][j] =
              __builtin_amdgcn_mfma_f32_16x16x32_bf16(a[i], bq[j], acc[i][j], 0, 0, 0);
    }
  };

  stage(Ab, As[0]);
  stage(Bb, Bs[0]);
  __syncthreads();
#pragma unroll
  for (int s = 0; s < 4; ++s) {
    if (s < 3) {
      stage(Ab + (s + 1) * 64, As[(s + 1) & 1]);
      stage(Bb + (s + 1) * 64, Bs[(s + 1) & 1]);
    }
    compute(As[s & 1], Bs[s & 1]);
    __syncthreads();
  }

  if (MODE == 5) {
    const int r_f = blockIdx.y >> 1;                // fixed r for this rc-tile
    const int cwave = (blockIdx.y & 1) * 128 + wr;  // c-coordinate base
    const float s1r = e1[r_f];
#pragma unroll
    for (int i = 0; i < 4; ++i) {
      int cb0 = cwave + i * 16 + lk * 4;
#pragma unroll
      for (int j = 0; j < 4; ++j) {
        int bb = colB + j * 16 + lr;  // batch index
        float c2r = e0[bb * 256 + r_f];
        u16x4 st;
#pragma unroll
        for (int e = 0; e < 4; ++e) {
          int cc = cb0 + e;
          float g = acc[i][j][e];
          if (cc == r_f) g += s1r;
          float v = SQ2PI_F * c2r * e0[bb * 256 + cc] * g;
          if (cc == r_f) v += e2[bb * 256 + cc];
          st[e] = bf16rne(v);
        }
        *(u16x4*)(outh + ((size_t)bb << 16) + (size_t)r_f * 256 + cb0) = st;
      }
    }
  } else if (MODE == 6) {
    float dpart[4] = {0.f, 0.f, 0.f, 0.f};
#pragma unroll
    for (int i = 0; i < 4; ++i) {
      int rb = rowA + i * 16 + lk * 4;
#pragma unroll
      for (int j = 0; j < 4; ++j) {
        int cc = colB + j * 16 + lr;
        u16x4 st;
        float dp = 0.f;
#pragma unroll
        for (int e = 0; e < 4; ++e) {
          float v = acc[i][j][e];
          st[e] = bf16rne(v);
          dp = fmaf(e0[(rb + e) * 256 + cc], v, dp);  // m2[r][c] * t3[r][c]
        }
        dpart[j] += dp;
        *(u16x4*)(outh + ((size_t)b << 16) + (size_t)cc * 256 + rb) = st;
      }
    }
#pragma unroll
    for (int j = 0; j < 4; ++j) {
      float s = dpart[j];
      s += __shfl_xor(s, 16, 64);
      s += __shfl_xor(s, 32, 64);
      if (l < 16) atomicAdd(&dsig[b * 256 + colB + j * 16 + l], s);
    }
  } else {  // MODE 8
#pragma unroll
    for (int i = 0; i < 4; ++i) {
      int rb = rowA + i * 16 + lk * 4;
#pragma unroll
      for (int j = 0; j < 4; ++j) {
        int cc = colB + j * 16 + lr;
        float c3c = e0[b * 256 + cc];
        f32x4 st;
#pragma unroll
        for (int e = 0; e < 4; ++e) {
          int rr = rb + e;
          float g = acc[i][j][e];
          if (rr == cc) g += e1[rr];
          float v = SQ2PI_F * e0[b * 256 + rr] * c3c * g;
          if (rr == cc) v += e2[b * 256 + cc];
          st[e] = v;
        }
        *(f32x4*)(outf + ((size_t)b << 16) + (size_t)cc * 256 + rb) = st;
      }
    }
  }
}

// ------------------------------------------------------------------

extern "C" void kernel_launch(void* const* d_in, const int* in_sizes, int n_in,
                              void* d_out, int out_size, void* d_ws, size_t ws_size,
                              hipStream_t stream) {
  const float* x = (const float*)d_in[0];
  const int* target = (const int*)d_in[1];
  const float* w0 = (const float*)d_in[2];
  const float* w1 = (const float*)d_in[3];
  const float* w2 = (const float*)d_in[4];
  const float* wlast = (const float*)d_in[5];
  const float* th0 = (const float*)d_in[6];
  const float* th1 = (const float*)d_in[7];
  const float* th2 = (const float*)d_in[8];
  const float* thlast = (const float*)d_in[9];

  float* W = (float*)d_ws;
  size_t o = 0;
  auto alloc = [&](size_t n) { float* p = W + o; o += n; return p; };
  float* m0 = alloc(200704);
  float* m1 = alloc(65536);
  float* m2 = alloc(65536);
  float* m1t = alloc(65536);
  float* mlast = alloc(2560);
  float* diagsig1 = alloc(256);  // zero-block start (66304 floats)
  float* s1 = alloc(256);
  float* s2 = alloc(256);
  float* diagsig3 = alloc(65536);
  float* x1bar = alloc(65536);
  float* d1 = alloc(65536);
  float* x2bar = alloc(65536);
  float* c2 = alloc(65536);
  float* d2p = alloc(65536);
  float* x3bar = alloc(65536);
  float* c3 = alloc(65536);
  float* d3p = alloc(65536);
  unsigned short* d1h = (unsigned short*)alloc(32768);     // 65536 bf16
  unsigned short* m2th = (unsigned short*)alloc(32768);    // 65536 bf16
  unsigned short* PtT3 = (unsigned short*)alloc(8388608);  // Pt then t3t (bf16)

  float* hlast = (float*)d_out;
  float* logp = hlast + 2560;
  float* xcov3_out = logp + 2560;
  float* loss = xcov3_out + 16777216;
  float* frac = loss + 1;
  // xcov2_hi borrows the xcov3 output slot; consumed by mode 6, then overwritten.
  unsigned short* xcov2h = (unsigned short*)xcov3_out;

  // 1) prep: all means/transposes + zero dsig1,s1,s2,dsig3 + zero loss/frac
  k_prep<<<1566, 256, 0, stream>>>(w0, w1, w2, wlast, m0, m1, m1t, m2, m2th,
                                   mlast, diagsig1, loss);

  // 2) column sums (fused)
  k_colsums<<<15, 256, 0, stream>>>(m0, m1, m2, diagsig1, s1, s2);

  // 3) Pt[rc][k] = m1t[r][k]*m1t[c][k]
  k_makeP<<<1024, 256, 0, stream>>>(m1t, PtT3);

  // 4) layer 1
  k_layer1<<<256, 256, 0, stream>>>(x, m0, diagsig1, th0, x1bar, d1, d1h);

  // 5) layer 2 small
  k_layer2_small<<<256, 256, 0, stream>>>(d1, x1bar, m1, s1, th1, x2bar, c2, d2p);

  // 6) xcov2 = MFMA(Pt, d1) + epilogue -> bf16 (in d_out slot)
  mfma_gemm<5><<<dim3(2, 512, 1), 256, 0, stream>>>(PtT3, d1h, c2, s1, d2p,
                                                    nullptr, xcov2h, nullptr);

  // 7) t3t = MFMA(xcov2, m2t), transposed bf16 store + diagsig3 atomics
  mfma_gemm<6><<<dim3(2, 2, 256), 256, 0, stream>>>(xcov2h, m2th, m2, nullptr,
                                                    nullptr, nullptr, PtT3, diagsig3);

  // 8) layer 3 small (h3 + diagsig3 -> x3bar, c3, d3p)
  k_layer3h<<<256, 256, 0, stream>>>(diagsig3, s2, x2bar, m2, th2, x3bar, c3, d3p);

  // 9) xcov3 = MFMA(m2t, t3t) + epilogue -> fp32 d_out
  mfma_gemm<8><<<dim3(2, 2, 256), 256, 0, stream>>>(m2th, PtT3, c3, s2, d3p,
                                                    xcov3_out, nullptr, nullptr);

  // 10) final layer + softmax + loss + acc (4 blocks, atomic reduce)
  k_final4<<<4, 64, 0, stream>>>(x3bar, mlast, thlast, target, hlast, logp, loss, frac);
}

// Round 6
// 207.870 us; speedup vs baseline: 10.5009x; 1.0826x over previous
//
#include <hip/hip_runtime.h>
#include <math.h>

#define SQ2PI_F 0.79788456f

typedef __attribute__((ext_vector_type(8))) short short8;
typedef __attribute__((ext_vector_type(4))) float f32x4;

__device__ inline unsigned short bf16rne(float x) {
  unsigned int u = __float_as_uint(x);
  u += 0x7fffu + ((u >> 16) & 1u);
  return (unsigned short)(u >> 16);
}
__device__ inline float bf2f(unsigned short u) {
  return __uint_as_float(((unsigned int)u) << 16);
}

// ------------------------------------------------------------------
// fused prep: means (+bf16 transposes), zero accumulators, zero loss/frac
// blocks [0,784) m0 | [784,1040) m1+m1th | [1040,1296) m2+m2th |
// [1296,1306) mlast (+loss/frac zero) | [1306,1309) zero 768 floats
// ------------------------------------------------------------------
__global__ void k_prep(const float* __restrict__ w0, const float* __restrict__ w1,
                       const float* __restrict__ w2, const float* __restrict__ wlast,
                       float* __restrict__ m0, float* __restrict__ m1,
                       unsigned short* __restrict__ m1th, float* __restrict__ m2,
                       unsigned short* __restrict__ m2th, float* __restrict__ mlast,
                       float* __restrict__ zbase, float* __restrict__ lf) {
  int b = blockIdx.x, t = threadIdx.x;
  if (b < 784) {
    int i = b * 256 + t;
    m0[i] = tanhf(0.5f * w0[i]);
  } else if (b < 1040) {
    int j = b - 784;
    float v = tanhf(0.5f * w1[j * 256 + t]);
    m1[j * 256 + t] = v;
    m1th[t * 256 + j] = bf16rne(v);   // m1th[r][k] = m1[k][r]
  } else if (b < 1296) {
    int j = b - 1040;
    float v = tanhf(0.5f * w2[j * 256 + t]);
    m2[j * 256 + t] = v;
    m2th[t * 256 + j] = bf16rne(v);   // m2th[i][j] = m2[j][i]
  } else if (b < 1306) {
    int i = (b - 1296) * 256 + t;
    if (i < 2560) mlast[i] = tanhf(0.5f * wlast[i]);
    if (b == 1296 && t < 2) lf[t] = 0.f;
  } else {
    int i = (b - 1306) * 256 + t;
    if (i < 768) zbase[i] = 0.f;
  }
}

// fused column sums: blocks 0..6 m0(112 rows) | 7..10 m1(64) | 11..14 m2(64)
__global__ void k_colsums(const float* __restrict__ m0, const float* __restrict__ m1,
                          const float* __restrict__ m2, float* __restrict__ dsig1,
                          float* __restrict__ s1, float* __restrict__ s2) {
  int b = blockIdx.x, j = threadIdx.x;
  const float* src;
  float* dst;
  int r0, rn;
  if (b < 7) { src = m0; dst = dsig1; r0 = b * 112; rn = r0 + 112; }
  else if (b < 11) { src = m1; dst = s1; r0 = (b - 7) * 64; rn = r0 + 64; }
  else { src = m2; dst = s2; r0 = (b - 11) * 64; rn = r0 + 64; }
  float acc = 0.f;
  for (int i = r0; i < rn; ++i) {
    float v = src[i * 256 + j];
    acc = fmaf(-v, v, acc + 1.0f);
  }
  atomicAdd(&dst[j], acc);
}

// layer 1: block=row r, thread=col j, K=784
__global__ void k_layer1(const float* __restrict__ x, const float* __restrict__ m0,
                         const float* __restrict__ diagsig1, const float* __restrict__ th0,
                         float* __restrict__ x1bar, float* __restrict__ d1) {
  __shared__ float xr[784];
  int r = blockIdx.x, j = threadIdx.x;
  for (int p = j; p < 784; p += 256) xr[p] = x[r * 784 + p];
  __syncthreads();
  float acc = 0.f;
#pragma unroll 8
  for (int k = 0; k < 784; ++k) acc = fmaf(xr[k], m0[k * 256 + j], acc);
  float rs = rsqrtf(diagsig1[j]);
  float xb = tanhf(SQ2PI_F * (acc + th0[j]) * rs);
  x1bar[r * 256 + j] = xb;
  d1[r * 256 + j] = 1.f - xb * xb;
}

// layer-2 small pass
__global__ void k_layer2_small(const float* __restrict__ d1, const float* __restrict__ x1bar,
                               const float* __restrict__ m1, const float* __restrict__ s1,
                               const float* __restrict__ th1,
                               float* __restrict__ x2bar, float* __restrict__ c2,
                               float* __restrict__ d2p) {
  int r = blockIdx.x, i = threadIdx.x;
  float accd = 0.f, acch = 0.f;
  for (int j = 0; j < 256; ++j) {
    float mm = m1[j * 256 + i];
    accd = fmaf(d1[r * 256 + j] * mm, mm, accd);
    acch = fmaf(x1bar[r * 256 + j], mm, acch);
  }
  float rs = rsqrtf(accd + s1[i]);
  float xb = tanhf(SQ2PI_F * (acch + th1[i]) * rs);
  x2bar[r * 256 + i] = xb;
  float d = 1.f - xb * xb;
  c2[r * 256 + i] = d * rs;
  d2p[r * 256 + i] = d;
}

// ------------------------------------------------------------------
// k_fused: one block (512 thr / 8 waves) per batch b. Whole Sigma-chain
// xcov2 -> diag(sigma3) -> (x3bar,c3,d3p) -> xcov3 with xcov2 resident
// in LDS (bf16, XOR-swizzled rows: chunk ^= (row&7)<<4).
// MFMA frags: A [row][k] (lr=row), B [col][k] (lr=col), C rows at lk*4+e,
// cols at lr (m89-verified mapping; identical to the passing round-5 code).
// ------------------------------------------------------------------
__global__ __launch_bounds__(512) void k_fused(
    const unsigned short* __restrict__ m1th, const unsigned short* __restrict__ m2th,
    const float* __restrict__ m2, const float* __restrict__ d1,
    const float* __restrict__ x2bar, const float* __restrict__ c2,
    const float* __restrict__ d2p, const float* __restrict__ s1,
    const float* __restrict__ s2, const float* __restrict__ th2,
    float* __restrict__ x3bar, float* __restrict__ xcov3) {
  extern __shared__ char lds[];
  char* XC = lds;                        // xcov2 bf16 [256 rows][512 B]
  char* TP = lds + 131072;               // panel bf16 [32 rows][512 B] (PW / t3p^T)
  float* c2L = (float*)(lds + 147456);
  float* d2pL = (float*)(lds + 148480);
  float* dsig = (float*)(lds + 149504);
  float* c3L = (float*)(lds + 150528);
  float* d3L = (float*)(lds + 151552);

  const int b = blockIdx.x;
  const int tid = threadIdx.x;
  const int l = tid & 63, w = tid >> 6;
  const int lr = l & 15, lk = l >> 4;

  if (tid < 256) {
    c2L[tid] = c2[b * 256 + tid];
    d2pL[tid] = d2p[b * 256 + tid];
    dsig[tid] = 0.f;
  }

  // ---------- phase 1: xcov2 -> XC (8 panels of 32 cols) ----------
  for (int cp = 0; cp < 8; ++cp) {
    __syncthreads();  // TP reuse + (cp=0) init visibility
    // weighted B panel: PW[c][k] = m1t[cp*32+c][k] * d1[b][k]
    for (int q = tid; q < 1024; q += 512) {
      int c = q >> 5, kc = q & 31;
      short8 mv = *(const short8*)(m1th + (size_t)(cp * 32 + c) * 256 + kc * 8);
      const float* dp = d1 + b * 256 + kc * 8;
      short8 pk;
#pragma unroll
      for (int e = 0; e < 8; ++e)
        pk[e] = (short)bf16rne(bf2f((unsigned short)mv[e]) * dp[e]);
      *(short8*)(TP + (c << 9) + ((kc << 4) ^ ((c & 7) << 4))) = pk;
    }
    __syncthreads();
    f32x4 acc[2][2];
#pragma unroll
    for (int i = 0; i < 2; ++i)
#pragma unroll
      for (int j = 0; j < 2; ++j) acc[i][j] = {0.f, 0.f, 0.f, 0.f};
#pragma unroll
    for (int ks = 0; ks < 8; ++ks) {
      short8 a[2], bq[2];
#pragma unroll
      for (int f = 0; f < 2; ++f) {
        a[f] = *(const short8*)(m1th + (size_t)(w * 32 + f * 16 + lr) * 256 + ks * 32 + lk * 8);
        int c = f * 16 + lr;
        bq[f] = *(const short8*)(TP + (c << 9) + ((ks * 64 + lk * 16) ^ ((c & 7) << 4)));
      }
#pragma unroll
      for (int i = 0; i < 2; ++i)
#pragma unroll
        for (int j = 0; j < 2; ++j)
          acc[i][j] = __builtin_amdgcn_mfma_f32_16x16x32_bf16(a[i], bq[j], acc[i][j], 0, 0, 0);
    }
    // epilogue -> XC bf16 (swizzled scatter)
#pragma unroll
    for (int i = 0; i < 2; ++i)
#pragma unroll
      for (int j = 0; j < 2; ++j) {
        int cc = cp * 32 + j * 16 + lr;
        float c2c = c2L[cc];
#pragma unroll
        for (int e = 0; e < 4; ++e) {
          int r = w * 32 + i * 16 + lk * 4 + e;
          float g = acc[i][j][e];
          if (r == cc) g += s1[r];
          float v = SQ2PI_F * c2L[r] * c2c * g;
          if (r == cc) v += d2pL[r];
          *(unsigned short*)(XC + (r << 9) + ((cc << 1) ^ ((r & 7) << 4))) = bf16rne(v);
        }
      }
  }
  __syncthreads();

  // ---------- loop A: diag(sigma3) only (t3 panels computed & discarded) ----------
  for (int lp = 0; lp < 8; ++lp) {
    f32x4 acc[2][2];
#pragma unroll
    for (int i = 0; i < 2; ++i)
#pragma unroll
      for (int j = 0; j < 2; ++j) acc[i][j] = {0.f, 0.f, 0.f, 0.f};
#pragma unroll
    for (int ks = 0; ks < 8; ++ks) {
      short8 a[2], bq[2];
#pragma unroll
      for (int f = 0; f < 2; ++f) {
        int j = w * 32 + f * 16 + lr;
        a[f] = *(const short8*)(XC + (j << 9) + ((ks * 64 + lk * 16) ^ ((j & 7) << 4)));
        bq[f] = *(const short8*)(m2th + (size_t)(lp * 32 + f * 16 + lr) * 256 + ks * 32 + lk * 8);
      }
#pragma unroll
      for (int i = 0; i < 2; ++i)
#pragma unroll
        for (int j = 0; j < 2; ++j)
          acc[i][j] = __builtin_amdgcn_mfma_f32_16x16x32_bf16(a[i], bq[j], acc[i][j], 0, 0, 0);
    }
    float dpart[2] = {0.f, 0.f};
#pragma unroll
    for (int jf = 0; jf < 2; ++jf)
#pragma unroll
      for (int lf = 0; lf < 2; ++lf) {
        int gl = lp * 32 + lf * 16 + lr;
#pragma unroll
        for (int e = 0; e < 4; ++e) {
          int j = w * 32 + jf * 16 + lk * 4 + e;
          dpart[lf] = fmaf(m2[j * 256 + gl], acc[jf][lf][e], dpart[lf]);
        }
      }
#pragma unroll
    for (int lf = 0; lf < 2; ++lf) {
      float s = dpart[lf];
      s += __shfl_xor(s, 16, 64);
      s += __shfl_xor(s, 32, 64);
      if (l < 16) atomicAdd(&dsig[lp * 32 + lf * 16 + l], s);
    }
  }
  __syncthreads();

  // ---------- phase 2.5: h3 / x3bar / c3 / d3p rows ----------
  if (tid < 256) {
    int i = tid;
    float acch = 0.f;
    for (int j = 0; j < 256; ++j)
      acch = fmaf(x2bar[b * 256 + j], m2[j * 256 + i], acch);
    float ds = dsig[i] + s2[i];
    float rs = rsqrtf(ds);
    float xb = tanhf(SQ2PI_F * (acch + th2[i]) * rs);
    x3bar[b * 256 + i] = xb;
    float d = 1.f - xb * xb;
    c3L[i] = d * rs;
    d3L[i] = d;
  }
  __syncthreads();

  // ---------- loop B: t3 panel -> TP, then sigma3 panel + epilogue -> d_out ----------
  for (int lp = 0; lp < 8; ++lp) {
    {
      f32x4 acc[2][2];
#pragma unroll
      for (int i = 0; i < 2; ++i)
#pragma unroll
        for (int j = 0; j < 2; ++j) acc[i][j] = {0.f, 0.f, 0.f, 0.f};
#pragma unroll
      for (int ks = 0; ks < 8; ++ks) {
        short8 a[2], bq[2];
#pragma unroll
        for (int f = 0; f < 2; ++f) {
          int j = w * 32 + f * 16 + lr;
          a[f] = *(const short8*)(XC + (j << 9) + ((ks * 64 + lk * 16) ^ ((j & 7) << 4)));
          bq[f] = *(const short8*)(m2th + (size_t)(lp * 32 + f * 16 + lr) * 256 + ks * 32 + lk * 8);
        }
#pragma unroll
        for (int i = 0; i < 2; ++i)
#pragma unroll
          for (int j = 0; j < 2; ++j)
            acc[i][j] = __builtin_amdgcn_mfma_f32_16x16x32_bf16(a[i], bq[j], acc[i][j], 0, 0, 0);
      }
      // store t3 panel transposed: TP[l][j] (bf16, swizzled)
#pragma unroll
      for (int jf = 0; jf < 2; ++jf)
#pragma unroll
        for (int lf = 0; lf < 2; ++lf) {
          int lloc = lf * 16 + lr;
#pragma unroll
          for (int e = 0; e < 4; ++e) {
            int j = w * 32 + jf * 16 + lk * 4 + e;
            *(unsigned short*)(TP + (lloc << 9) + ((j << 1) ^ ((lloc & 7) << 4))) =
                bf16rne(acc[jf][lf][e]);
          }
        }
    }
    __syncthreads();
    {
      f32x4 acc[2][2];
#pragma unroll
      for (int i = 0; i < 2; ++i)
#pragma unroll
        for (int j = 0; j < 2; ++j) acc[i][j] = {0.f, 0.f, 0.f, 0.f};
#pragma unroll
      for (int ks = 0; ks < 8; ++ks) {
        short8 a[2], bq[2];
#pragma unroll
        for (int f = 0; f < 2; ++f) {
          a[f] = *(const short8*)(m2th + (size_t)(w * 32 + f * 16 + lr) * 256 + ks * 32 + lk * 8);
          int lloc = f * 16 + lr;
          bq[f] = *(const short8*)(TP + (lloc << 9) + ((ks * 64 + lk * 16) ^ ((lloc & 7) << 4)));
        }
#pragma unroll
        for (int i = 0; i < 2; ++i)
#pragma unroll
          for (int j = 0; j < 2; ++j)
            acc[i][j] = __builtin_amdgcn_mfma_f32_16x16x32_bf16(a[i], bq[j], acc[i][j], 0, 0, 0);
      }
      // epilogue: xcov3[b][gl][i0..] (symmetric-transposed f32x4 store)
#pragma unroll
      for (int ifg = 0; ifg < 2; ++ifg)
#pragma unroll
        for (int lf = 0; lf < 2; ++lf) {
          int gl = lp * 32 + lf * 16 + lr;
          float cg = c3L[gl];
          int i0 = w * 32 + ifg * 16 + lk * 4;
          f32x4 st;
#pragma unroll
          for (int e = 0; e < 4; ++e) {
            int i = i0 + e;
            float g = acc[ifg][lf][e];
            if (i == gl) g += s2[i];
            float v = SQ2PI_F * c3L[i] * cg * g;
            if (i == gl) v += d3L[i];
            st[e] = v;
          }
          *(f32x4*)(xcov3 + ((size_t)b << 16) + (size_t)gl * 256 + i0) = st;
        }
    }
    __syncthreads();
  }
}

// final layer + log_softmax + loss + frac_correct. grid 4 x block 64
__global__ void k_final4(const float* __restrict__ x3bar, const float* __restrict__ mlast,
                         const float* __restrict__ thlast, const int* __restrict__ target,
                         float* __restrict__ hlast_out, float* __restrict__ logp_out,
                         float* __restrict__ loss_out, float* __restrict__ frac_out) {
  __shared__ float Wl[2560];
  int t = threadIdx.x;
  int r = blockIdx.x * 64 + t;
  for (int p = t; p < 2560; p += 64) Wl[p] = mlast[p];
  __syncthreads();
  float acc[10];
#pragma unroll
  for (int c = 0; c < 10; ++c) acc[c] = thlast[c];
  for (int j = 0; j < 256; ++j) {
    float xv = x3bar[r * 256 + j];
#pragma unroll
    for (int c = 0; c < 10; ++c) acc[c] = fmaf(xv, Wl[j * 10 + c], acc[c]);
  }
#pragma unroll
  for (int c = 0; c < 10; ++c) hlast_out[r * 10 + c] = acc[c];
  float mx = acc[0];
  int am = 0;
#pragma unroll
  for (int c = 1; c < 10; ++c)
    if (acc[c] > mx) { mx = acc[c]; am = c; }
  float se = 0.f;
#pragma unroll
  for (int c = 0; c < 10; ++c) se += expf(acc[c] - mx);
  float lse = logf(se);
#pragma unroll
  for (int c = 0; c < 10; ++c) logp_out[r * 10 + c] = acc[c] - mx - lse;
  int tg = target[r];
  float lossc = -(acc[tg] - mx - lse) * (1.f / 256.f);
  float corr = (am == tg) ? (1.f / 256.f) : 0.f;
#pragma unroll
  for (int off = 32; off > 0; off >>= 1) {
    lossc += __shfl_down(lossc, off);
    corr += __shfl_down(corr, off);
  }
  if (t == 0) {
    atomicAdd(loss_out, lossc);
    atomicAdd(frac_out, corr);
  }
}

// ------------------------------------------------------------------

extern "C" void kernel_launch(void* const* d_in, const int* in_sizes, int n_in,
                              void* d_out, int out_size, void* d_ws, size_t ws_size,
                              hipStream_t stream) {
  const float* x = (const float*)d_in[0];
  const int* target = (const int*)d_in[1];
  const float* w0 = (const float*)d_in[2];
  const float* w1 = (const float*)d_in[3];
  const float* w2 = (const float*)d_in[4];
  const float* wlast = (const float*)d_in[5];
  const float* th0 = (const float*)d_in[6];
  const float* th1 = (const float*)d_in[7];
  const float* th2 = (const float*)d_in[8];
  const float* thlast = (const float*)d_in[9];

  float* W = (float*)d_ws;
  size_t o = 0;
  auto alloc = [&](size_t n) { float* p = W + o; o += n; return p; };
  float* m0 = alloc(200704);
  float* m1 = alloc(65536);
  float* m2 = alloc(65536);
  float* mlast = alloc(2560);
  float* diagsig1 = alloc(256);  // zero-block start (768 floats, contiguous)
  float* s1 = alloc(256);
  float* s2 = alloc(256);
  float* x1bar = alloc(65536);
  float* d1 = alloc(65536);
  float* x2bar = alloc(65536);
  float* c2 = alloc(65536);
  float* d2p = alloc(65536);
  float* x3bar = alloc(65536);
  unsigned short* m1th = (unsigned short*)alloc(32768);  // 65536 bf16
  unsigned short* m2th = (unsigned short*)alloc(32768);  // 65536 bf16

  float* hlast = (float*)d_out;
  float* logp = hlast + 2560;
  float* xcov3_out = logp + 2560;
  float* loss = xcov3_out + 16777216;
  float* frac = loss + 1;

  // opt-in to 149 KB dynamic LDS for k_fused (runtime config call, not a
  // stream op -> graph-capture safe; idempotent and deterministic)
  const int FUSED_LDS = 152576;
  hipFuncSetAttribute((const void*)k_fused,
                      hipFuncAttributeMaxDynamicSharedMemorySize, FUSED_LDS);

  // 1) prep
  k_prep<<<1309, 256, 0, stream>>>(w0, w1, w2, wlast, m0, m1, m1th, m2, m2th,
                                   mlast, diagsig1, loss);
  // 2) column sums
  k_colsums<<<15, 256, 0, stream>>>(m0, m1, m2, diagsig1, s1, s2);
  // 3) layer 1
  k_layer1<<<256, 256, 0, stream>>>(x, m0, diagsig1, th0, x1bar, d1);
  // 4) layer 2 small
  k_layer2_small<<<256, 256, 0, stream>>>(d1, x1bar, m1, s1, th1, x2bar, c2, d2p);
  // 5) fused sigma-chain: xcov2 (LDS) -> diag(sigma3) -> x3bar/c3/d3p -> xcov3
  k_fused<<<256, 512, FUSED_LDS, stream>>>(m1th, m2th, m2, d1, x2bar, c2, d2p,
                                           s1, s2, th2, x3bar, xcov3_out);
  // 6) final layer + softmax + loss + acc
  k_final4<<<4, 64, 0, stream>>>(x3bar, mlast, thlast, target, hlast, logp, loss, frac);
}

// Round 7
// 207.634 us; speedup vs baseline: 10.5128x; 1.0011x over previous
//
#include <hip/hip_runtime.h>
#include <math.h>

#define SQ2PI_F 0.79788456f

typedef __attribute__((ext_vector_type(8))) short short8;
typedef __attribute__((ext_vector_type(4))) float f32x4;
typedef __attribute__((ext_vector_type(4))) unsigned short u16x4;

__device__ inline unsigned short bf16rne(float x) {
  unsigned int u = __float_as_uint(x);
  u += 0x7fffu + ((u >> 16) & 1u);
  return (unsigned short)(u >> 16);
}
__device__ inline float bf2f(unsigned short u) {
  return __uint_as_float(((unsigned int)u) << 16);
}

// ------------------------------------------------------------------
// fused prep: means (+bf16 transposes), zero accumulators, zero loss/frac
// ------------------------------------------------------------------
__global__ void k_prep(const float* __restrict__ w0, const float* __restrict__ w1,
                       const float* __restrict__ w2, const float* __restrict__ wlast,
                       float* __restrict__ m0, float* __restrict__ m1,
                       unsigned short* __restrict__ m1th, float* __restrict__ m2,
                       unsigned short* __restrict__ m2th, float* __restrict__ mlast,
                       float* __restrict__ zbase, float* __restrict__ lf) {
  int b = blockIdx.x, t = threadIdx.x;
  if (b < 784) {
    int i = b * 256 + t;
    m0[i] = tanhf(0.5f * w0[i]);
  } else if (b < 1040) {
    int j = b - 784;
    float v = tanhf(0.5f * w1[j * 256 + t]);
    m1[j * 256 + t] = v;
    m1th[t * 256 + j] = bf16rne(v);   // m1th[r][k] = m1[k][r]
  } else if (b < 1296) {
    int j = b - 1040;
    float v = tanhf(0.5f * w2[j * 256 + t]);
    m2[j * 256 + t] = v;
    m2th[t * 256 + j] = bf16rne(v);   // m2th[i][j] = m2[j][i]
  } else if (b < 1306) {
    int i = (b - 1296) * 256 + t;
    if (i < 2560) mlast[i] = tanhf(0.5f * wlast[i]);
    if (b == 1296 && t < 2) lf[t] = 0.f;
  } else {
    int i = (b - 1306) * 256 + t;
    if (i < 768) zbase[i] = 0.f;
  }
}

// fused column sums: blocks 0..6 m0(112 rows) | 7..10 m1(64) | 11..14 m2(64)
__global__ void k_colsums(const float* __restrict__ m0, const float* __restrict__ m1,
                          const float* __restrict__ m2, float* __restrict__ dsig1,
                          float* __restrict__ s1, float* __restrict__ s2) {
  int b = blockIdx.x, j = threadIdx.x;
  const float* src;
  float* dst;
  int r0, rn;
  if (b < 7) { src = m0; dst = dsig1; r0 = b * 112; rn = r0 + 112; }
  else if (b < 11) { src = m1; dst = s1; r0 = (b - 7) * 64; rn = r0 + 64; }
  else { src = m2; dst = s2; r0 = (b - 11) * 64; rn = r0 + 64; }
  float acc = 0.f;
  for (int i = r0; i < rn; ++i) {
    float v = src[i * 256 + j];
    acc = fmaf(-v, v, acc + 1.0f);
  }
  atomicAdd(&dst[j], acc);
}

// layer 1: block=row r, thread=col j, K=784
__global__ void k_layer1(const float* __restrict__ x, const float* __restrict__ m0,
                         const float* __restrict__ diagsig1, const float* __restrict__ th0,
                         float* __restrict__ x1bar, float* __restrict__ d1) {
  __shared__ float xr[784];
  int r = blockIdx.x, j = threadIdx.x;
  for (int p = j; p < 784; p += 256) xr[p] = x[r * 784 + p];
  __syncthreads();
  float acc = 0.f;
#pragma unroll 8
  for (int k = 0; k < 784; ++k) acc = fmaf(xr[k], m0[k * 256 + j], acc);
  float rs = rsqrtf(diagsig1[j]);
  float xb = tanhf(SQ2PI_F * (acc + th0[j]) * rs);
  x1bar[r * 256 + j] = xb;
  d1[r * 256 + j] = 1.f - xb * xb;
}

// layer-2 pass + h3: diagsig2/h2 -> x2bar (LDS only), c2, d2p; h3 = x2bar@m2 + th2
__global__ void k_layer2(const float* __restrict__ d1, const float* __restrict__ x1bar,
                         const float* __restrict__ m1, const float* __restrict__ m2,
                         const float* __restrict__ s1, const float* __restrict__ th1,
                         const float* __restrict__ th2,
                         float* __restrict__ c2, float* __restrict__ d2p,
                         float* __restrict__ h3bar) {
  __shared__ float sx[256];
  int r = blockIdx.x, i = threadIdx.x;
  float accd = 0.f, acch = 0.f;
  for (int j = 0; j < 256; ++j) {
    float mm = m1[j * 256 + i];
    accd = fmaf(d1[r * 256 + j] * mm, mm, accd);
    acch = fmaf(x1bar[r * 256 + j], mm, acch);
  }
  float rs = rsqrtf(accd + s1[i]);
  float xb = tanhf(SQ2PI_F * (acch + th1[i]) * rs);
  float d = 1.f - xb * xb;
  c2[r * 256 + i] = d * rs;
  d2p[r * 256 + i] = d;
  sx[i] = xb;
  __syncthreads();
  float acch3 = 0.f;
  for (int j = 0; j < 256; ++j)
    acch3 = fmaf(sx[j], m2[j * 256 + i], acch3);
  h3bar[r * 256 + i] = acch3 + th2[i];
}

// ------------------------------------------------------------------
// k_fused: one block (512 thr / 8 waves) per batch b.
//   phase 1 (no barriers): xcov2 -> XC (bf16, transposed-symmetric store,
//            8B contiguous swizzled stores; weighted B built in registers)
//   loop B (8 panels): t3 panel -> TP (transposed, 8B stores) -> barrier ->
//            sigma3 panel accumulated into PERSISTENT regs sig[8][2][2];
//            diag extracted at panel lp==w -> dsig LDS (no atomics)
//   c3 phase: x3bar/c3/d3 from dsig+h3bar (tid<256)
//   epilogue: all 8 panels from sig regs -> fp32 xcov3 (d_out)
// Swizzle convention both sides: byte ^= (row&7)<<4 within 512B rows.
// MFMA frags: A [row][k] lr=row; B [col][k] lr=col; C rows lk*4+e, cols lr.
// ------------------------------------------------------------------
__global__ __launch_bounds__(512, 2) void k_fused(
    const unsigned short* __restrict__ m1th, const unsigned short* __restrict__ m2th,
    const float* __restrict__ d1, const float* __restrict__ c2,
    const float* __restrict__ d2p, const float* __restrict__ s1,
    const float* __restrict__ s2, const float* __restrict__ h3bar,
    float* __restrict__ x3bar, float* __restrict__ xcov3) {
  extern __shared__ char lds[];
  char* XC = lds;                       // xcov2 bf16 [256][512B]
  char* TP = lds + 131072;              // t3 panel^T bf16 [32][512B]
  float* c2L = (float*)(lds + 147456);
  float* d2pL = (float*)(lds + 148480);
  float* dsig = (float*)(lds + 149504);
  float* c3L = (float*)(lds + 150528);
  float* d3L = (float*)(lds + 151552);

  const int b = blockIdx.x;
  const int tid = threadIdx.x;
  const int l = tid & 63, w = tid >> 6;
  const int lr = l & 15, lk = l >> 4;
  const int R = w * 32;

  if (tid < 256) {
    c2L[tid] = c2[b * 256 + tid];
    d2pL[tid] = d2p[b * 256 + tid];
  }
  __syncthreads();

  const float* d1b = d1 + b * 256;

  // hoisted phase-1 A-frags: m1th rows R..R+31, all k (live only in phase 1)
  short8 af[2][8];
#pragma unroll
  for (int f = 0; f < 2; ++f)
#pragma unroll
    for (int ks = 0; ks < 8; ++ks)
      af[f][ks] = *(const short8*)(m1th + (size_t)(R + f * 16 + lr) * 256 + ks * 32 + lk * 8);

  // ---------- phase 1: xcov2 -> XC ----------
  for (int cp = 0; cp < 8; ++cp) {
    f32x4 acc[2][2];
#pragma unroll
    for (int i = 0; i < 2; ++i)
#pragma unroll
      for (int j = 0; j < 2; ++j) acc[i][j] = {0.f, 0.f, 0.f, 0.f};
#pragma unroll
    for (int ks = 0; ks < 8; ++ks) {
      f32x4 dv0 = *(const f32x4*)(d1b + ks * 32 + lk * 8);
      f32x4 dv1 = *(const f32x4*)(d1b + ks * 32 + lk * 8 + 4);
      short8 bq[2];
#pragma unroll
      for (int f = 0; f < 2; ++f) {
        short8 mv = *(const short8*)(m1th + (size_t)(cp * 32 + f * 16 + lr) * 256 + ks * 32 + lk * 8);
#pragma unroll
        for (int e = 0; e < 4; ++e) {
          bq[f][e] = (short)bf16rne(bf2f((unsigned short)mv[e]) * dv0[e]);
          bq[f][e + 4] = (short)bf16rne(bf2f((unsigned short)mv[e + 4]) * dv1[e]);
        }
      }
#pragma unroll
      for (int i = 0; i < 2; ++i)
#pragma unroll
        for (int j = 0; j < 2; ++j)
          acc[i][j] = __builtin_amdgcn_mfma_f32_16x16x32_bf16(af[i][ks], bq[j], acc[i][j], 0, 0, 0);
    }
    // epilogue: transposed-symmetric store XC[cc][r0..r0+3] (8B, swizzled)
#pragma unroll
    for (int i = 0; i < 2; ++i) {
      int r0 = R + i * 16 + lk * 4;
#pragma unroll
      for (int j = 0; j < 2; ++j) {
        int cc = cp * 32 + j * 16 + lr;
        float c2c = c2L[cc];
        u16x4 st;
#pragma unroll
        for (int e = 0; e < 4; ++e) {
          int r = r0 + e;
          float g = acc[i][j][e];
          if (r == cc) g += s1[r];
          float v = SQ2PI_F * c2L[r] * c2c * g;
          if (r == cc) v += d2pL[r];
          st[e] = bf16rne(v);
        }
        *(u16x4*)(XC + (cc << 9) + (((unsigned)(r0 << 1)) ^ ((cc & 7) << 4))) = st;
      }
    }
  }
  __syncthreads();

  // ---------- loop B: t3 once, sigma3 into persistent regs ----------
  f32x4 sig[8][2][2];
#pragma unroll
  for (int lp = 0; lp < 8; ++lp)
#pragma unroll
    for (int i = 0; i < 2; ++i)
#pragma unroll
      for (int j = 0; j < 2; ++j) sig[lp][i][j] = {0.f, 0.f, 0.f, 0.f};

#pragma unroll
  for (int lp = 0; lp < 8; ++lp) {
    // step 1: t3p[j, l] = sum_k XC[j,k] * m2[k,l];  j = wave rows, l = panel cols
    f32x4 at[2][2];
#pragma unroll
    for (int i = 0; i < 2; ++i)
#pragma unroll
      for (int j = 0; j < 2; ++j) at[i][j] = {0.f, 0.f, 0.f, 0.f};
#pragma unroll
    for (int ks = 0; ks < 8; ++ks) {
      short8 a[2], bq[2];
#pragma unroll
      for (int f = 0; f < 2; ++f) {
        int jr = R + f * 16 + lr;
        a[f] = *(const short8*)(XC + (jr << 9) + (((unsigned)(ks * 64 + lk * 16)) ^ ((jr & 7) << 4)));
        bq[f] = *(const short8*)(m2th + (size_t)(lp * 32 + f * 16 + lr) * 256 + ks * 32 + lk * 8);
      }
#pragma unroll
      for (int i = 0; i < 2; ++i)
#pragma unroll
        for (int j = 0; j < 2; ++j)
          at[i][j] = __builtin_amdgcn_mfma_f32_16x16x32_bf16(a[i], bq[j], at[i][j], 0, 0, 0);
    }
    // store t3 panel transposed: TP[l][j0..j0+3] (8B, swizzled)
#pragma unroll
    for (int jf = 0; jf < 2; ++jf) {
      int j0 = R + jf * 16 + lk * 4;
#pragma unroll
      for (int lf = 0; lf < 2; ++lf) {
        int lloc = lf * 16 + lr;
        u16x4 st;
#pragma unroll
        for (int e = 0; e < 4; ++e) st[e] = bf16rne(at[jf][lf][e]);
        *(u16x4*)(TP + (lloc << 9) + (((unsigned)(j0 << 1)) ^ ((lloc & 7) << 4))) = st;
      }
    }
    __syncthreads();
    // step 2: sigma3[i, l] += sum_j m2th[i][j] * TP[l][j]
#pragma unroll
    for (int ks = 0; ks < 8; ++ks) {
      short8 a[2], bq[2];
#pragma unroll
      for (int f = 0; f < 2; ++f) {
        a[f] = *(const short8*)(m2th + (size_t)(R + f * 16 + lr) * 256 + ks * 32 + lk * 8);
        int lloc = f * 16 + lr;
        bq[f] = *(const short8*)(TP + (lloc << 9) + (((unsigned)(ks * 64 + lk * 16)) ^ ((lloc & 7) << 4)));
      }
#pragma unroll
      for (int i = 0; i < 2; ++i)
#pragma unroll
        for (int j = 0; j < 2; ++j)
          sig[lp][i][j] = __builtin_amdgcn_mfma_f32_16x16x32_bf16(a[i], bq[j], sig[lp][i][j], 0, 0, 0);
    }
    // diag of sigma3 lives in panel lp == w for this wave's rows
    if (lp == w) {
      if (lk == (lr >> 2)) {
        int e = lr & 3;
#pragma unroll
        for (int ifg = 0; ifg < 2; ++ifg) {
          f32x4 v4 = sig[lp][ifg][ifg];
          float v = (e == 0) ? v4[0] : (e == 1) ? v4[1] : (e == 2) ? v4[2] : v4[3];
          dsig[R + ifg * 16 + lr] = v;
        }
      }
    }
    __syncthreads();  // TP consumed; also final sync before c3 phase at lp==7
  }

  // ---------- c3 phase ----------
  if (tid < 256) {
    float ds = dsig[tid] + s2[tid];
    float rs = rsqrtf(ds);
    float xb = tanhf(SQ2PI_F * h3bar[b * 256 + tid] * rs);
    x3bar[b * 256 + tid] = xb;
    float d = 1.f - xb * xb;
    c3L[tid] = d * rs;
    d3L[tid] = d;
  }
  __syncthreads();

  // ---------- epilogue: xcov3 from sig regs (transposed-symmetric store) ----------
#pragma unroll
  for (int lp = 0; lp < 8; ++lp) {
#pragma unroll
    for (int ifg = 0; ifg < 2; ++ifg) {
      int i0 = R + ifg * 16 + lk * 4;
#pragma unroll
      for (int lf = 0; lf < 2; ++lf) {
        int gl = lp * 32 + lf * 16 + lr;
        float cg = c3L[gl];
        f32x4 st;
#pragma unroll
        for (int e = 0; e < 4; ++e) {
          int i = i0 + e;
          float g = sig[lp][ifg][lf][e];
          if (i == gl) g += s2[i];
          float v = SQ2PI_F * c3L[i] * cg * g;
          if (i == gl) v += d3L[i];
          st[e] = v;
        }
        *(f32x4*)(xcov3 + ((size_t)b << 16) + (size_t)gl * 256 + i0) = st;
      }
    }
  }
}

// final layer + log_softmax + loss + frac_correct. grid 4 x block 64
__global__ void k_final4(const float* __restrict__ x3bar, const float* __restrict__ mlast,
                         const float* __restrict__ thlast, const int* __restrict__ target,
                         float* __restrict__ hlast_out, float* __restrict__ logp_out,
                         float* __restrict__ loss_out, float* __restrict__ frac_out) {
  __shared__ float Wl[2560];
  int t = threadIdx.x;
  int r = blockIdx.x * 64 + t;
  for (int p = t; p < 2560; p += 64) Wl[p] = mlast[p];
  __syncthreads();
  float acc[10];
#pragma unroll
  for (int c = 0; c < 10; ++c) acc[c] = thlast[c];
  for (int j = 0; j < 256; ++j) {
    float xv = x3bar[r * 256 + j];
#pragma unroll
    for (int c = 0; c < 10; ++c) acc[c] = fmaf(xv, Wl[j * 10 + c], acc[c]);
  }
#pragma unroll
  for (int c = 0; c < 10; ++c) hlast_out[r * 10 + c] = acc[c];
  float mx = acc[0];
  int am = 0;
#pragma unroll
  for (int c = 1; c < 10; ++c)
    if (acc[c] > mx) { mx = acc[c]; am = c; }
  float se = 0.f;
#pragma unroll
  for (int c = 0; c < 10; ++c) se += expf(acc[c] - mx);
  float lse = logf(se);
#pragma unroll
  for (int c = 0; c < 10; ++c) logp_out[r * 10 + c] = acc[c] - mx - lse;
  int tg = target[r];
  float lossc = -(acc[tg] - mx - lse) * (1.f / 256.f);
  float corr = (am == tg) ? (1.f / 256.f) : 0.f;
#pragma unroll
  for (int off = 32; off > 0; off >>= 1) {
    lossc += __shfl_down(lossc, off);
    corr += __shfl_down(corr, off);
  }
  if (t == 0) {
    atomicAdd(loss_out, lossc);
    atomicAdd(frac_out, corr);
  }
}

// ------------------------------------------------------------------

extern "C" void kernel_launch(void* const* d_in, const int* in_sizes, int n_in,
                              void* d_out, int out_size, void* d_ws, size_t ws_size,
                              hipStream_t stream) {
  const float* x = (const float*)d_in[0];
  const int* target = (const int*)d_in[1];
  const float* w0 = (const float*)d_in[2];
  const float* w1 = (const float*)d_in[3];
  const float* w2 = (const float*)d_in[4];
  const float* wlast = (const float*)d_in[5];
  const float* th0 = (const float*)d_in[6];
  const float* th1 = (const float*)d_in[7];
  const float* th2 = (const float*)d_in[8];
  const float* thlast = (const float*)d_in[9];

  float* W = (float*)d_ws;
  size_t o = 0;
  auto alloc = [&](size_t n) { float* p = W + o; o += n; return p; };
  float* m0 = alloc(200704);
  float* m1 = alloc(65536);
  float* m2 = alloc(65536);
  float* mlast = alloc(2560);
  float* diagsig1 = alloc(256);  // zero-block start (768 floats, contiguous)
  float* s1 = alloc(256);
  float* s2 = alloc(256);
  float* x1bar = alloc(65536);
  float* d1 = alloc(65536);
  float* c2 = alloc(65536);
  float* d2p = alloc(65536);
  float* h3bar = alloc(65536);
  float* x3bar = alloc(65536);
  unsigned short* m1th = (unsigned short*)alloc(32768);  // 65536 bf16
  unsigned short* m2th = (unsigned short*)alloc(32768);  // 65536 bf16

  float* hlast = (float*)d_out;
  float* logp = hlast + 2560;
  float* xcov3_out = logp + 2560;
  float* loss = xcov3_out + 16777216;
  float* frac = loss + 1;

  const int FUSED_LDS = 152576;
  hipFuncSetAttribute((const void*)k_fused,
                      hipFuncAttributeMaxDynamicSharedMemorySize, FUSED_LDS);

  // 1) prep
  k_prep<<<1309, 256, 0, stream>>>(w0, w1, w2, wlast, m0, m1, m1th, m2, m2th,
                                   mlast, diagsig1, loss);
  // 2) column sums
  k_colsums<<<15, 256, 0, stream>>>(m0, m1, m2, diagsig1, s1, s2);
  // 3) layer 1
  k_layer1<<<256, 256, 0, stream>>>(x, m0, diagsig1, th0, x1bar, d1);
  // 4) layer 2 (+h3)
  k_layer2<<<256, 256, 0, stream>>>(d1, x1bar, m1, m2, s1, th1, th2, c2, d2p, h3bar);
  // 5) fused sigma-chain
  k_fused<<<256, 512, FUSED_LDS, stream>>>(m1th, m2th, d1, c2, d2p, s1, s2,
                                           h3bar, x3bar, xcov3_out);
  // 6) final layer + softmax + loss + acc
  k_final4<<<4, 64, 0, stream>>>(x3bar, mlast, thlast, target, hlast, logp, loss, frac);
}

// Round 8
// 206.935 us; speedup vs baseline: 10.5483x; 1.0034x over previous
//
#include <hip/hip_runtime.h>
#include <math.h>

#define SQ2PI_F 0.79788456f

typedef __attribute__((ext_vector_type(8))) short short8;
typedef __attribute__((ext_vector_type(4))) float f32x4;
typedef __attribute__((ext_vector_type(4))) unsigned short u16x4;

__device__ inline unsigned short bf16rne(float x) {
  unsigned int u = __float_as_uint(x);
  u += 0x7fffu + ((u >> 16) & 1u);
  return (unsigned short)(u >> 16);
}
__device__ inline float bf2f(unsigned short u) {
  return __uint_as_float(((unsigned int)u) << 16);
}

// ------------------------------------------------------------------
// fused prep: means (+bf16 transposes), zero accumulators, zero loss/frac
// ------------------------------------------------------------------
__global__ void k_prep(const float* __restrict__ w0, const float* __restrict__ w1,
                       const float* __restrict__ w2, const float* __restrict__ wlast,
                       float* __restrict__ m0, float* __restrict__ m1,
                       unsigned short* __restrict__ m1th, float* __restrict__ m2,
                       unsigned short* __restrict__ m2th, float* __restrict__ mlast,
                       float* __restrict__ zbase, float* __restrict__ lf) {
  int b = blockIdx.x, t = threadIdx.x;
  if (b < 784) {
    int i = b * 256 + t;
    m0[i] = tanhf(0.5f * w0[i]);
  } else if (b < 1040) {
    int j = b - 784;
    float v = tanhf(0.5f * w1[j * 256 + t]);
    m1[j * 256 + t] = v;
    m1th[t * 256 + j] = bf16rne(v);   // m1th[r][k] = m1[k][r]
  } else if (b < 1296) {
    int j = b - 1040;
    float v = tanhf(0.5f * w2[j * 256 + t]);
    m2[j * 256 + t] = v;
    m2th[t * 256 + j] = bf16rne(v);   // m2th[i][j] = m2[j][i]
  } else if (b < 1306) {
    int i = (b - 1296) * 256 + t;
    if (i < 2560) mlast[i] = tanhf(0.5f * wlast[i]);
    if (b == 1296 && t < 2) lf[t] = 0.f;
  } else {
    int i = (b - 1306) * 256 + t;
    if (i < 768) zbase[i] = 0.f;
  }
}

// fused column sums: blocks 0..6 m0(112 rows) | 7..10 m1(64) | 11..14 m2(64)
__global__ void k_colsums(const float* __restrict__ m0, const float* __restrict__ m1,
                          const float* __restrict__ m2, float* __restrict__ dsig1,
                          float* __restrict__ s1, float* __restrict__ s2) {
  int b = blockIdx.x, j = threadIdx.x;
  const float* src;
  float* dst;
  int r0, rn;
  if (b < 7) { src = m0; dst = dsig1; r0 = b * 112; rn = r0 + 112; }
  else if (b < 11) { src = m1; dst = s1; r0 = (b - 7) * 64; rn = r0 + 64; }
  else { src = m2; dst = s2; r0 = (b - 11) * 64; rn = r0 + 64; }
  float acc = 0.f;
  for (int i = r0; i < rn; ++i) {
    float v = src[i * 256 + j];
    acc = fmaf(-v, v, acc + 1.0f);
  }
  atomicAdd(&dst[j], acc);
}

// layer 1: block=row r, thread=col j, K=784
__global__ void k_layer1(const float* __restrict__ x, const float* __restrict__ m0,
                         const float* __restrict__ diagsig1, const float* __restrict__ th0,
                         float* __restrict__ x1bar, float* __restrict__ d1) {
  __shared__ float xr[784];
  int r = blockIdx.x, j = threadIdx.x;
  for (int p = j; p < 784; p += 256) xr[p] = x[r * 784 + p];
  __syncthreads();
  float acc = 0.f;
#pragma unroll 8
  for (int k = 0; k < 784; ++k) acc = fmaf(xr[k], m0[k * 256 + j], acc);
  float rs = rsqrtf(diagsig1[j]);
  float xb = tanhf(SQ2PI_F * (acc + th0[j]) * rs);
  x1bar[r * 256 + j] = xb;
  d1[r * 256 + j] = 1.f - xb * xb;
}

// layer-2 pass + h3: x2bar kept in LDS only; emits c2, d2p, h3bar
__global__ void k_layer2(const float* __restrict__ d1, const float* __restrict__ x1bar,
                         const float* __restrict__ m1, const float* __restrict__ m2,
                         const float* __restrict__ s1, const float* __restrict__ th1,
                         const float* __restrict__ th2,
                         float* __restrict__ c2, float* __restrict__ d2p,
                         float* __restrict__ h3bar) {
  __shared__ float sx[256];
  int r = blockIdx.x, i = threadIdx.x;
  float accd = 0.f, acch = 0.f;
  for (int j = 0; j < 256; ++j) {
    float mm = m1[j * 256 + i];
    accd = fmaf(d1[r * 256 + j] * mm, mm, accd);
    acch = fmaf(x1bar[r * 256 + j], mm, acch);
  }
  float rs = rsqrtf(accd + s1[i]);
  float xb = tanhf(SQ2PI_F * (acch + th1[i]) * rs);
  float d = 1.f - xb * xb;
  c2[r * 256 + i] = d * rs;
  d2p[r * 256 + i] = d;
  sx[i] = xb;
  __syncthreads();
  float acch3 = 0.f;
  for (int j = 0; j < 256; ++j)
    acch3 = fmaf(sx[j], m2[j * 256 + i], acch3);
  h3bar[r * 256 + i] = acch3 + th2[i];
}

// ------------------------------------------------------------------
// k_fused: one block (512 thr / 8 waves) per batch.
// LDS: only a double-buffered 16KB exchange panel + small vectors (~40KB).
// phase 1: xcov2 computed 32-col panels; d1-weighting folded into the
//   once-hoisted A-frags (af_w). Panel stored TRANSPOSED into TPd[cp&1];
//   after the barrier, wave w==cp pulls its 32 xcov2 rows into afX regs.
// loop B (pipelined): step1(lp): t3 panel = afX x m2th -> TPd[lp&1]
//   (transposed); step2(lp-1): sig[lp-1] += m2th x TPd[(lp-1)&1]; one
//   barrier per segment. diag(sigma3) extracted at lp==w into dsig.
// c3 phase + epilogue from sig (AGPRs) -> fp32 xcov3 (d_out).
// Swizzle both sides: byte ^= (row&7)<<4 within 512B rows (rule 21).
// MFMA frags: A [row][k] lr=row; B [col][k] lr=col; C rows lk*4+e, cols lr.
// ------------------------------------------------------------------
__global__ __launch_bounds__(512, 2) void k_fused(
    const unsigned short* __restrict__ m1th, const unsigned short* __restrict__ m2th,
    const float* __restrict__ d1, const float* __restrict__ c2,
    const float* __restrict__ d2p, const float* __restrict__ s1,
    const float* __restrict__ s2, const float* __restrict__ h3bar,
    float* __restrict__ x3bar, float* __restrict__ xcov3) {
  __shared__ __align__(16) unsigned short TPd[2][8192];  // 2 x 16KB panels
  __shared__ float c2L[256], d2pL[256], s1L[256], s2L[256];
  __shared__ float dsig[256], c3L[256], d3L[256];

  const int b = blockIdx.x;
  const int tid = threadIdx.x;
  const int l = tid & 63, w = tid >> 6;
  const int lr = l & 15, lk = l >> 4;
  const int R = w * 32;

  if (tid < 256) {
    c2L[tid] = c2[b * 256 + tid];
    d2pL[tid] = d2p[b * 256 + tid];
    s1L[tid] = s1[tid];
    s2L[tid] = s2[tid];
  }

  const float* d1b = d1 + b * 256;

  // hoisted, d1-weighted A-frags for phase 1 (once per block)
  short8 af_w[2][8];
#pragma unroll
  for (int ks = 0; ks < 8; ++ks) {
    f32x4 dv0 = *(const f32x4*)(d1b + ks * 32 + lk * 8);
    f32x4 dv1 = *(const f32x4*)(d1b + ks * 32 + lk * 8 + 4);
#pragma unroll
    for (int f = 0; f < 2; ++f) {
      short8 mv = *(const short8*)(m1th + (size_t)(R + f * 16 + lr) * 256 + ks * 32 + lk * 8);
#pragma unroll
      for (int e = 0; e < 4; ++e) {
        af_w[f][ks][e] = (short)bf16rne(bf2f((unsigned short)mv[e]) * dv0[e]);
        af_w[f][ks][e + 4] = (short)bf16rne(bf2f((unsigned short)mv[e + 4]) * dv1[e]);
      }
    }
  }
  __syncthreads();

  short8 afX[2][8];  // this wave's 32 xcov2 rows (filled at cp == w)

  // ---------- phase 1: xcov2 panels, exchange via TPd ----------
#pragma unroll
  for (int cp = 0; cp < 8; ++cp) {
    char* XP = (char*)TPd[cp & 1];
    f32x4 acc[2][2];
#pragma unroll
    for (int i = 0; i < 2; ++i)
#pragma unroll
      for (int j = 0; j < 2; ++j) acc[i][j] = {0.f, 0.f, 0.f, 0.f};
#pragma unroll
    for (int ks = 0; ks < 8; ++ks) {
      short8 bq[2];
#pragma unroll
      for (int f = 0; f < 2; ++f)
        bq[f] = *(const short8*)(m1th + (size_t)(cp * 32 + f * 16 + lr) * 256 + ks * 32 + lk * 8);
#pragma unroll
      for (int i = 0; i < 2; ++i)
#pragma unroll
        for (int j = 0; j < 2; ++j)
          acc[i][j] = __builtin_amdgcn_mfma_f32_16x16x32_bf16(af_w[i][ks], bq[j], acc[i][j], 0, 0, 0);
    }
    // epilogue -> XP transposed (xcov2 symmetric)
#pragma unroll
    for (int i = 0; i < 2; ++i) {
      int r0 = R + i * 16 + lk * 4;
#pragma unroll
      for (int j = 0; j < 2; ++j) {
        int p = j * 16 + lr;
        int cc = cp * 32 + p;
        float c2c = c2L[cc];
        u16x4 st;
#pragma unroll
        for (int e = 0; e < 4; ++e) {
          int r = r0 + e;
          float g = acc[i][j][e];
          if (r == cc) g += s1L[r];
          float v = SQ2PI_F * c2L[r] * c2c * g;
          if (r == cc) v += d2pL[r];
          st[e] = bf16rne(v);
        }
        *(u16x4*)(XP + (p << 9) + (((unsigned)(r0 << 1)) ^ ((p & 7) << 4))) = st;
      }
    }
    __syncthreads();
    if (w == cp) {
#pragma unroll
      for (int f = 0; f < 2; ++f) {
        int p2 = f * 16 + lr;
#pragma unroll
        for (int ks = 0; ks < 8; ++ks)
          afX[f][ks] = *(const short8*)(XP + (p2 << 9) + (((unsigned)(ks * 64 + lk * 16)) ^ ((p2 & 7) << 4)));
      }
    }
  }

  // ---------- loop B: pipelined t3-panel / sigma3 accumulation ----------
  f32x4 sig[8][2][2];
#pragma unroll
  for (int lp = 0; lp < 8; ++lp)
#pragma unroll
    for (int i = 0; i < 2; ++i)
#pragma unroll
      for (int j = 0; j < 2; ++j) sig[lp][i][j] = {0.f, 0.f, 0.f, 0.f};

#define STEP1(LP)                                                                          \
  {                                                                                        \
    char* TB = (char*)TPd[(LP) & 1];                                                       \
    f32x4 at[2][2];                                                                        \
    _Pragma("unroll") for (int i = 0; i < 2; ++i) _Pragma("unroll")                        \
        for (int j = 0; j < 2; ++j) at[i][j] = {0.f, 0.f, 0.f, 0.f};                       \
    _Pragma("unroll") for (int ks = 0; ks < 8; ++ks) {                                     \
      short8 bq[2];                                                                        \
      _Pragma("unroll") for (int f = 0; f < 2; ++f) bq[f] =                                \
          *(const short8*)(m2th + (size_t)((LP)*32 + f * 16 + lr) * 256 + ks * 32 + lk * 8); \
      _Pragma("unroll") for (int i = 0; i < 2; ++i) _Pragma("unroll")                      \
          for (int j = 0; j < 2; ++j) at[i][j] =                                           \
              __builtin_amdgcn_mfma_f32_16x16x32_bf16(afX[i][ks], bq[j], at[i][j], 0, 0, 0); \
    }                                                                                      \
    _Pragma("unroll") for (int i = 0; i < 2; ++i) {                                        \
      int j0 = R + i * 16 + lk * 4;                                                        \
      _Pragma("unroll") for (int jf = 0; jf < 2; ++jf) {                                   \
        int p = jf * 16 + lr;                                                              \
        u16x4 st;                                                                          \
        _Pragma("unroll") for (int e = 0; e < 4; ++e) st[e] = bf16rne(at[i][jf][e]);       \
        *(u16x4*)(TB + (p << 9) + (((unsigned)(j0 << 1)) ^ ((p & 7) << 4))) = st;          \
      }                                                                                    \
    }                                                                                      \
  }

#define STEP2(LP)                                                                          \
  {                                                                                        \
    const char* TB = (const char*)TPd[(LP) & 1];                                           \
    _Pragma("unroll") for (int ks = 0; ks < 8; ++ks) {                                     \
      short8 a2[2], bq2[2];                                                                \
      _Pragma("unroll") for (int f = 0; f < 2; ++f) {                                      \
        a2[f] = *(const short8*)(m2th + (size_t)(R + f * 16 + lr) * 256 + ks * 32 + lk * 8); \
        int p = f * 16 + lr;                                                               \
        bq2[f] = *(const short8*)(TB + (p << 9) +                                          \
                                  (((unsigned)(ks * 64 + lk * 16)) ^ ((p & 7) << 4)));     \
      }                                                                                    \
      _Pragma("unroll") for (int i = 0; i < 2; ++i) _Pragma("unroll")                      \
          for (int j = 0; j < 2; ++j) sig[LP][i][j] =                                      \
              __builtin_amdgcn_mfma_f32_16x16x32_bf16(a2[i], bq2[j], sig[LP][i][j], 0, 0, 0); \
    }                                                                                      \
    if (w == (LP) && lk == (lr >> 2)) {                                                    \
      _Pragma("unroll") for (int lf = 0; lf < 2; ++lf) {                                   \
        f32x4 v4 = sig[LP][lf][lf];                                                        \
        dsig[R + lf * 16 + lr] = v4[lr & 3];                                               \
      }                                                                                    \
    }                                                                                      \
  }

  STEP1(0)
  __syncthreads();
  STEP1(1) STEP2(0)
  __syncthreads();
  STEP1(2) STEP2(1)
  __syncthreads();
  STEP1(3) STEP2(2)
  __syncthreads();
  STEP1(4) STEP2(3)
  __syncthreads();
  STEP1(5) STEP2(4)
  __syncthreads();
  STEP1(6) STEP2(5)
  __syncthreads();
  STEP1(7) STEP2(6)
  __syncthreads();
  STEP2(7)
  __syncthreads();
#undef STEP1
#undef STEP2

  // ---------- c3 phase ----------
  if (tid < 256) {
    float ds = dsig[tid] + s2L[tid];
    float rs = rsqrtf(ds);
    float xb = tanhf(SQ2PI_F * h3bar[b * 256 + tid] * rs);
    x3bar[b * 256 + tid] = xb;
    float d = 1.f - xb * xb;
    c3L[tid] = d * rs;
    d3L[tid] = d;
  }
  __syncthreads();

  // ---------- epilogue: xcov3 from sig (transposed-symmetric store) ----------
#pragma unroll
  for (int lp = 0; lp < 8; ++lp) {
#pragma unroll
    for (int ifg = 0; ifg < 2; ++ifg) {
      int i0 = R + ifg * 16 + lk * 4;
#pragma unroll
      for (int lf = 0; lf < 2; ++lf) {
        int gl = lp * 32 + lf * 16 + lr;
        float cg = c3L[gl];
        f32x4 st;
#pragma unroll
        for (int e = 0; e < 4; ++e) {
          int i = i0 + e;
          float g = sig[lp][ifg][lf][e];
          if (i == gl) g += s2L[i];
          float v = SQ2PI_F * c3L[i] * cg * g;
          if (i == gl) v += d3L[i];
          st[e] = v;
        }
        *(f32x4*)(xcov3 + ((size_t)b << 16) + (size_t)gl * 256 + i0) = st;
      }
    }
  }
}

// final layer + log_softmax + loss + frac_correct. grid 4 x block 64
__global__ void k_final4(const float* __restrict__ x3bar, const float* __restrict__ mlast,
                         const float* __restrict__ thlast, const int* __restrict__ target,
                         float* __restrict__ hlast_out, float* __restrict__ logp_out,
                         float* __restrict__ loss_out, float* __restrict__ frac_out) {
  __shared__ float Wl[2560];
  int t = threadIdx.x;
  int r = blockIdx.x * 64 + t;
  for (int p = t; p < 2560; p += 64) Wl[p] = mlast[p];
  __syncthreads();
  float acc[10];
#pragma unroll
  for (int c = 0; c < 10; ++c) acc[c] = thlast[c];
  for (int j = 0; j < 256; ++j) {
    float xv = x3bar[r * 256 + j];
#pragma unroll
    for (int c = 0; c < 10; ++c) acc[c] = fmaf(xv, Wl[j * 10 + c], acc[c]);
  }
#pragma unroll
  for (int c = 0; c < 10; ++c) hlast_out[r * 10 + c] = acc[c];
  float mx = acc[0];
  int am = 0;
#pragma unroll
  for (int c = 1; c < 10; ++c)
    if (acc[c] > mx) { mx = acc[c]; am = c; }
  float se = 0.f;
#pragma unroll
  for (int c = 0; c < 10; ++c) se += expf(acc[c] - mx);
  float lse = logf(se);
#pragma unroll
  for (int c = 0; c < 10; ++c) logp_out[r * 10 + c] = acc[c] - mx - lse;
  int tg = target[r];
  float lossc = -(acc[tg] - mx - lse) * (1.f / 256.f);
  float corr = (am == tg) ? (1.f / 256.f) : 0.f;
#pragma unroll
  for (int off = 32; off > 0; off >>= 1) {
    lossc += __shfl_down(lossc, off);
    corr += __shfl_down(corr, off);
  }
  if (t == 0) {
    atomicAdd(loss_out, lossc);
    atomicAdd(frac_out, corr);
  }
}

// ------------------------------------------------------------------

extern "C" void kernel_launch(void* const* d_in, const int* in_sizes, int n_in,
                              void* d_out, int out_size, void* d_ws, size_t ws_size,
                              hipStream_t stream) {
  const float* x = (const float*)d_in[0];
  const int* target = (const int*)d_in[1];
  const float* w0 = (const float*)d_in[2];
  const float* w1 = (const float*)d_in[3];
  const float* w2 = (const float*)d_in[4];
  const float* wlast = (const float*)d_in[5];
  const float* th0 = (const float*)d_in[6];
  const float* th1 = (const float*)d_in[7];
  const float* th2 = (const float*)d_in[8];
  const float* thlast = (const float*)d_in[9];

  float* W = (float*)d_ws;
  size_t o = 0;
  auto alloc = [&](size_t n) { float* p = W + o; o += n; return p; };
  float* m0 = alloc(200704);
  float* m1 = alloc(65536);
  float* m2 = alloc(65536);
  float* mlast = alloc(2560);
  float* diagsig1 = alloc(256);  // zero-block start (768 floats, contiguous)
  float* s1 = alloc(256);
  float* s2 = alloc(256);
  float* x1bar = alloc(65536);
  float* d1 = alloc(65536);
  float* c2 = alloc(65536);
  float* d2p = alloc(65536);
  float* h3bar = alloc(65536);
  float* x3bar = alloc(65536);
  unsigned short* m1th = (unsigned short*)alloc(32768);  // 65536 bf16
  unsigned short* m2th = (unsigned short*)alloc(32768);  // 65536 bf16

  float* hlast = (float*)d_out;
  float* logp = hlast + 2560;
  float* xcov3_out = logp + 2560;
  float* loss = xcov3_out + 16777216;
  float* frac = loss + 1;

  // 1) prep
  k_prep<<<1309, 256, 0, stream>>>(w0, w1, w2, wlast, m0, m1, m1th, m2, m2th,
                                   mlast, diagsig1, loss);
  // 2) column sums
  k_colsums<<<15, 256, 0, stream>>>(m0, m1, m2, diagsig1, s1, s2);
  // 3) layer 1
  k_layer1<<<256, 256, 0, stream>>>(x, m0, diagsig1, th0, x1bar, d1);
  // 4) layer 2 (+h3)
  k_layer2<<<256, 256, 0, stream>>>(d1, x1bar, m1, m2, s1, th1, th2, c2, d2p, h3bar);
  // 5) fused sigma-chain (small-LDS, register-resident xcov2 slices)
  k_fused<<<256, 512, 0, stream>>>(m1th, m2th, d1, c2, d2p, s1, s2,
                                   h3bar, x3bar, xcov3_out);
  // 6) final layer + softmax + loss + acc
  k_final4<<<4, 64, 0, stream>>>(x3bar, mlast, thlast, target, hlast, logp, loss, frac);
}